// Round 12
// baseline (771.517 us; speedup 1.0000x reference)
//
#include <hip/hip_runtime.h>
#include <hip/hip_bf16.h>
#include <math.h>

typedef __hip_bfloat16 bf16;
typedef unsigned short us;
typedef __attribute__((ext_vector_type(8))) short short8;
typedef __attribute__((ext_vector_type(4))) float floatx4;

#define EPI_SPLIT    1
#define EPI_STORE    2
#define EPI_RESID    4

#define INV_SQRT_N 0.17677669529663687f   /* 1/sqrt(32) */
#define INV_SQRT3  0.5773502691896258f
#define INV_SQRT2  0.7071067811865476f
#define C_OLD      0.8944271909999159f    /* 1/sqrt(1.25) */
#define C_NEW      0.4472135954999579f
#define PI_F       3.14159265358979323846f
#define SQRT3_F    1.7320508075688772f
#define BESSEL_PREF 0.6324555320336759f   /* sqrt(2/5) */

__device__ __forceinline__ float b2f(bf16 x) { return __bfloat162float(x); }
__device__ __forceinline__ bf16  f2b(float x) { return __float2bfloat16(x); }
__device__ __forceinline__ us f2bu(float x) {
  bf16 h = f2b(x); us u; __builtin_memcpy(&u, &h, 2); return u;
}
__device__ __forceinline__ float silu_f(float v) { return v / (1.f + __expf(-v)); }
__device__ __forceinline__ floatx4 mfma16(short8 a, short8 b, floatx4 c) {
  return __builtin_amdgcn_mfma_f32_16x16x32_bf16(a, b, c, 0, 0, 0);
}
__device__ __forceinline__ short8 ld8(const void* p) {
  return *reinterpret_cast<const short8*>(p);
}
#define ZERO8 ((short8){0,0,0,0,0,0,0,0})

// ---------------------------------------------------------------------------
// CSR build
// ---------------------------------------------------------------------------
__global__ __launch_bounds__(256) void k_deg(
    const int* __restrict__ eidx, int E, int* __restrict__ deg) {
  int e = blockIdx.x * 256 + threadIdx.x;
  if (e < E) atomicAdd(&deg[eidx[E + e]], 1);
}

__global__ __launch_bounds__(1024) void k_scan(
    const int* __restrict__ deg, int N,
    int* __restrict__ rowptr, int* __restrict__ cursor) {
  __shared__ int part[1024];
  int t = threadIdx.x;
  int C = (N + 1023) / 1024;
  int base = t * C;
  int s = 0;
  for (int i = 0; i < C; ++i) { int idx = base + i; if (idx < N) s += deg[idx]; }
  part[t] = s;
  __syncthreads();
  for (int off = 1; off < 1024; off <<= 1) {
    int v = (t >= off) ? part[t - off] : 0;
    __syncthreads();
    part[t] += v;
    __syncthreads();
  }
  int excl = (t == 0) ? 0 : part[t - 1];
  for (int i = 0; i < C; ++i) {
    int idx = base + i;
    if (idx < N) { rowptr[idx] = excl; cursor[idx] = excl; excl += deg[idx]; }
  }
  if (t == 0) rowptr[N] = part[1023];
}

__global__ __launch_bounds__(256) void k_fill(
    const int* __restrict__ eidx, int E, int* __restrict__ cursor,
    int* __restrict__ eord, int* __restrict__ cent) {
  int e = blockIdx.x * 256 + threadIdx.x;
  if (e >= E) return;
  int c = eidx[E + e];
  int slot = atomicAdd(&cursor[c], 1);
  eord[slot] = e;
  cent[slot] = c;
}

// ---------------------------------------------------------------------------
// per-slot geometry + A64 row build: [nattr[c](16)|nattr[s](16)|ef(8)|0(24)]
// ---------------------------------------------------------------------------
__global__ __launch_bounds__(256) void k_geom(
    const float* __restrict__ coords, const float* __restrict__ nattr,
    const int* __restrict__ eidx, const int* __restrict__ eord, int E,
    float* __restrict__ fcut, float* __restrict__ Yb, bf16* __restrict__ a64) {
  int j = blockIdx.x * 256 + threadIdx.x;
  if (j >= E) return;
  int e = eord[j];
  int s = eidx[e], c = eidx[E + e];
  float dx = coords[c*3+0] - coords[s*3+0];
  float dy = coords[c*3+1] - coords[s*3+1];
  float dz = coords[c*3+2] - coords[s*3+2];
  float r = sqrtf(dx*dx + dy*dy + dz*dz + 1e-12f);
  float u = r * 0.2f;
  float u3 = u*u*u;
  float u6 = u3*u3, u7 = u6*u, u8 = u7*u;
  float fc = 1.f - 28.f*u6 + 48.f*u7 - 21.f*u8;
  fc = (u < 1.f) ? fc : 0.f;
  float inv_r = 1.f / r;
  fcut[j] = fc;
  Yb[j*4+0] = 1.f;
  Yb[j*4+1] = SQRT3_F * dx * inv_r;
  Yb[j*4+2] = SQRT3_F * dy * inv_r;
  Yb[j*4+3] = SQRT3_F * dz * inv_r;
  bf16* row = a64 + (long)j * 64;
  #pragma unroll
  for (int i = 0; i < 16; ++i) row[i]      = f2b(nattr[(long)c*16 + i]);
  #pragma unroll
  for (int i = 0; i < 16; ++i) row[16 + i] = f2b(nattr[(long)s*16 + i]);
  float pref = BESSEL_PREF * inv_r * fc;
  #pragma unroll
  for (int n = 1; n <= 8; ++n)
    row[32 + n - 1] = f2b(pref * sinf((float)n * PI_F * u));
  #pragma unroll
  for (int i = 40; i < 64; ++i) row[i] = f2b(0.f);
}

// ---------------------------------------------------------------------------
// merged weight prep: fp32 W[k][n] -> bf16 Wt[n][k]; W2b0 padded to 64x64.
// ---------------------------------------------------------------------------
__device__ __forceinline__ void wp(const float* W, us* Wt, int K, int NOUT, int t) {
  int n = t / K, k = t % K;
  Wt[n * K + k] = f2bu(W[k * NOUT + n]);
}

__global__ __launch_bounds__(256) void k_wprep_all(
    const float* W2b0, const float* W2b1, const float* W2b2,
    const float* Wenv0, const float* Wlat0, const float* Wlat1,
    const float* Wenv1, const float* Wfin0, const float* Wfin1,
    const float* Ws0, const float* Wv0,
    us* W2b0p, us* W2b1t, us* W2b2t, us* Wenv0t, us* Wlat0t, us* Wlat1t,
    us* Wenv1t, us* Wfin0t, us* Wfin1t, us* Wmixt) {
  int t = blockIdx.x * 256 + threadIdx.x;
  if (t < 8192)  { wp(W2b1,  W2b1t,  64, 128, t); return; } t -= 8192;
  if (t < 16384) { wp(W2b2,  W2b2t, 128, 128, t); return; } t -= 16384;
  if (t < 16384) { wp(Wenv0, Wenv0t,128, 128, t); return; } t -= 16384;
  if (t < 24576) { wp(Wlat0, Wlat0t,192, 128, t); return; } t -= 24576;
  if (t < 16384) { wp(Wlat1, Wlat1t,128, 128, t); return; } t -= 16384;
  if (t < 8192)  { wp(Wenv1, Wenv1t,128,  64, t); return; } t -= 8192;
  if (t < 24576) { wp(Wfin0, Wfin0t,192, 128, t); return; } t -= 24576;
  if (t < 16384) { wp(Wfin1, Wfin1t,128, 128, t); return; } t -= 16384;
  if (t < 4096)  {
    int n = t >> 6, k = t & 63;
    W2b0p[n * 64 + k] = (k < 40) ? f2bu(W2b0[k * 64 + n]) : 0;
    return;
  } t -= 4096;
  if (t < 5120) {
    int o = t / 160, k = t % 160;
    float v = (k < 64) ? Ws0[k * 32 + o] : Wv0[(k - 64) * 32 + o];
    Wmixt[o * 160 + k] = f2bu(v);
  }
}

// ---------------------------------------------------------------------------
// env gather (CSR, slot-ordered)
// ---------------------------------------------------------------------------
__global__ __launch_bounds__(256) void k_envg(
    const bf16* __restrict__ wenv, const float* __restrict__ Yb,
    const int* __restrict__ rowptr, int N, float* __restrict__ env) {
  int t = blockIdx.x * 256 + threadIdx.x;
  if (t >= N * 32) return;
  int n = t >> 5, m = t & 31;
  int j0 = rowptr[n], j1 = rowptr[n + 1];
  float a0 = 0.f, a1 = 0.f, a2 = 0.f, a3 = 0.f;
  for (int j = j0; j < j1; ++j) {
    float w0 = b2f(wenv[(long)j*64 + 2*m]);
    float w1 = b2f(wenv[(long)j*64 + 2*m + 1]);
    float4 y = *reinterpret_cast<const float4*>(&Yb[(long)j*4]);
    a0 += w0;
    a1 += w1 * y.y;
    a2 += w1 * y.z;
    a3 += w1 * y.w;
  }
  *reinterpret_cast<float4*>(&env[(long)n*128 + m*4]) = make_float4(a0, a1, a2, a3);
}

// ---------------------------------------------------------------------------
// node gather (CSR, slot-ordered) -> d_out
// ---------------------------------------------------------------------------
__global__ __launch_bounds__(256) void k_nodeg(
    const bf16* __restrict__ lat, const int* __restrict__ rowptr,
    int N, float* __restrict__ out) {
  int t = blockIdx.x * 256 + threadIdx.x;
  if (t >= N * 128) return;
  int n = t >> 7, j = t & 127;
  int j0 = rowptr[n], j1 = rowptr[n + 1];
  float s = 0.f;
  for (int q = j0; q < j1; ++q)
    s += b2f(lat[(long)q*128 + j]);
  out[t] = s * INV_SQRT_N;
}

// ---------------------------------------------------------------------------
// MFMA GEMM: 64 edges x NOUT; whole-A staged flat into LDS once, W fragments
// in VGPRs. 1 barrier, 17 KB LDS.
// ---------------------------------------------------------------------------
template<int NOUT, int EPI>
__global__ __launch_bounds__(256) void mgemm(
    const bf16* __restrict__ A, const us* __restrict__ Wt,
    bf16* __restrict__ out1, bf16* __restrict__ out2, float scale, int E) {
  constexpr int K = 128, KP = 136, NC = 4;
  constexpr int CT = NOUT / 64;
  __shared__ __align__(16) us As[64 * KP];
  int tid = threadIdx.x;
  int lane = tid & 63, w = tid >> 6;
  int nl = lane & 15, quad = lane >> 4;
  long e0 = (long)blockIdx.x * 64;

  short8 wf[NC][CT];
  #pragma unroll
  for (int kc = 0; kc < NC; ++kc)
    #pragma unroll
    for (int ct = 0; ct < CT; ++ct)
      wf[kc][ct] = ld8(Wt + (long)(w*CT*16 + ct*16 + nl) * K + kc*32 + quad*8);

  #pragma unroll
  for (int it = 0; it < 4; ++it) {
    int i = tid + it * 256;
    int row = i >> 4, col = (i & 15) * 8;
    long eg = e0 + row;
    short8 v = (eg < E) ? ld8(A + eg * 128 + col) : ZERO8;
    *(short8*)&As[row * KP + col] = v;
  }
  __syncthreads();

  floatx4 acc[4][CT];
  #pragma unroll
  for (int i = 0; i < 4; ++i)
    #pragma unroll
    for (int j = 0; j < CT; ++j) acc[i][j] = (floatx4){0.f,0.f,0.f,0.f};
  #pragma unroll
  for (int kc = 0; kc < NC; ++kc) {
    short8 af[4];
    #pragma unroll
    for (int et = 0; et < 4; ++et)
      af[et] = ld8(&As[(et*16 + nl) * KP + kc*32 + quad*8]);
    #pragma unroll
    for (int et = 0; et < 4; ++et)
      #pragma unroll
      for (int ct = 0; ct < CT; ++ct)
        acc[et][ct] = mfma16(af[et], wf[kc][ct], acc[et][ct]);
  }

  #pragma unroll
  for (int et = 0; et < 4; ++et)
    #pragma unroll
    for (int ct = 0; ct < CT; ++ct)
      #pragma unroll
      for (int r = 0; r < 4; ++r) {
        long eg = e0 + et*16 + quad*4 + r;
        if (eg >= E) continue;
        int col = w*CT*16 + ct*16 + nl;
        float v = acc[et][ct][r] * scale;
        if constexpr (EPI == EPI_SPLIT) {
          if (col < 64) out1[eg * 64 + col] = f2b(v);
          else          out2[eg * 64 + (col - 64)] = f2b(v);
        } else { // EPI_STORE
          out1[eg * NOUT + col] = f2b(v);
        }
      }
}

// ---------------------------------------------------------------------------
// Three-layer fused two-body MLP: a64(40p) ->silu 64 ->silu 128 ->128 *fcut.
// LDS union: one 18.4 KB buffer serves As | H0 | Hs -> 8 blocks/CU.
// ---------------------------------------------------------------------------
__global__ __launch_bounds__(256) void mfused3(
    const bf16* __restrict__ a64, const us* __restrict__ W0p,
    const us* __restrict__ W1t, const us* __restrict__ W2t,
    bf16* __restrict__ lat, const float* __restrict__ fcut,
    float s40, float s64s, float s128, int E) {
  constexpr int AP = 72, HP = 136;
  __shared__ __align__(16) us SB[64 * 144];   // As[64*72] | H0[64*72]; Hs aliases
  us* As = SB;
  us* H0 = SB + 64 * AP;
  us* Hs = SB;                                // overwrites As∪H0 after barrier
  int tid = threadIdx.x;
  int lane = tid & 63, w = tid >> 6;
  int nl = lane & 15, quad = lane >> 4;
  long e0 = (long)blockIdx.x * 64;

  short8 w0f[2], w1f[2][2], w2f[4][2];
  #pragma unroll
  for (int kc = 0; kc < 2; ++kc)
    w0f[kc] = ld8(W0p + (w*16 + nl) * 64 + kc*32 + quad*8);
  #pragma unroll
  for (int kc = 0; kc < 2; ++kc)
    #pragma unroll
    for (int ct = 0; ct < 2; ++ct)
      w1f[kc][ct] = ld8(W1t + (long)(w*32 + ct*16 + nl) * 64 + kc*32 + quad*8);
  #pragma unroll
  for (int kc = 0; kc < 4; ++kc)
    #pragma unroll
    for (int ct = 0; ct < 2; ++ct)
      w2f[kc][ct] = ld8(W2t + (long)(w*32 + ct*16 + nl) * 128 + kc*32 + quad*8);

  #pragma unroll
  for (int it = 0; it < 2; ++it) {
    int i = tid + it * 256;
    int row = i >> 3, col = (i & 7) * 8;
    long eg = e0 + row;
    short8 v = (eg < E) ? ld8(a64 + eg * 64 + col) : ZERO8;
    *(short8*)&As[row * AP + col] = v;
  }
  __syncthreads();

  // layer 0: 64(40p) -> 64, silu -> H0 (disjoint from As)
  floatx4 a0[4];
  #pragma unroll
  for (int i = 0; i < 4; ++i) a0[i] = (floatx4){0.f,0.f,0.f,0.f};
  #pragma unroll
  for (int kc = 0; kc < 2; ++kc) {
    short8 af[4];
    #pragma unroll
    for (int et = 0; et < 4; ++et)
      af[et] = ld8(&As[(et*16 + nl) * AP + kc*32 + quad*8]);
    #pragma unroll
    for (int et = 0; et < 4; ++et) a0[et] = mfma16(af[et], w0f[kc], a0[et]);
  }
  #pragma unroll
  for (int et = 0; et < 4; ++et)
    #pragma unroll
    for (int r = 0; r < 4; ++r)
      H0[(et*16 + quad*4 + r) * AP + w*16 + nl] = f2bu(silu_f(a0[et][r] * s40));
  __syncthreads();

  // layer 1: 64 -> 128, silu (accumulate in regs; Hs write deferred)
  floatx4 acc[4][2];
  #pragma unroll
  for (int i = 0; i < 4; ++i)
    #pragma unroll
    for (int j = 0; j < 2; ++j) acc[i][j] = (floatx4){0.f,0.f,0.f,0.f};
  #pragma unroll
  for (int kc = 0; kc < 2; ++kc) {
    short8 af[4];
    #pragma unroll
    for (int et = 0; et < 4; ++et)
      af[et] = ld8(&H0[(et*16 + nl) * AP + kc*32 + quad*8]);
    #pragma unroll
    for (int et = 0; et < 4; ++et)
      #pragma unroll
      for (int ct = 0; ct < 2; ++ct)
        acc[et][ct] = mfma16(af[et], w1f[kc][ct], acc[et][ct]);
  }
  __syncthreads();   // all H0 reads complete before Hs overwrites SB

  #pragma unroll
  for (int et = 0; et < 4; ++et)
    #pragma unroll
    for (int ct = 0; ct < 2; ++ct)
      #pragma unroll
      for (int r = 0; r < 4; ++r)
        Hs[(et*16 + quad*4 + r) * HP + w*32 + ct*16 + nl] =
            f2bu(silu_f(acc[et][ct][r] * s64s));
  __syncthreads();

  // layer 2: 128 -> 128, *fcut
  #pragma unroll
  for (int i = 0; i < 4; ++i)
    #pragma unroll
    for (int j = 0; j < 2; ++j) acc[i][j] = (floatx4){0.f,0.f,0.f,0.f};
  #pragma unroll
  for (int kc = 0; kc < 4; ++kc) {
    short8 af[4];
    #pragma unroll
    for (int et = 0; et < 4; ++et)
      af[et] = ld8(&Hs[(et*16 + nl) * HP + kc*32 + quad*8]);
    #pragma unroll
    for (int et = 0; et < 4; ++et)
      #pragma unroll
      for (int ct = 0; ct < 2; ++ct)
        acc[et][ct] = mfma16(af[et], w2f[kc][ct], acc[et][ct]);
  }
  #pragma unroll
  for (int et = 0; et < 4; ++et)
    #pragma unroll
    for (int ct = 0; ct < 2; ++ct)
      #pragma unroll
      for (int r = 0; r < 4; ++r) {
        long eg = e0 + et*16 + quad*4 + r;
        if (eg >= E) continue;
        lat[eg * 128 + w*32 + ct*16 + nl] =
            f2b(acc[et][ct][r] * s128 * fcut[eg]);
      }
}

// ---------------------------------------------------------------------------
// Two-layer fused MLP: [lat(128)|scal(64)] ->silu 128 ->128 -> residual.
// LDS union: one 25.6 KB buffer serves As | Hs -> 6 blocks/CU (was 3).
// ---------------------------------------------------------------------------
template<int EPI>
__global__ __launch_bounds__(256) void mfused(
    const bf16* __restrict__ A, const bf16* __restrict__ A2,
    const us* __restrict__ W0t, const us* __restrict__ W1t,
    bf16* __restrict__ outb, const float* __restrict__ fcut,
    float scale0, float scale1, int E) {
  constexpr int K = 192, KP = 200, NC0 = 6, HP = 136;
  __shared__ __align__(16) us SB[64 * KP];   // As stride-200; Hs stride-136 alias
  us* As = SB;
  us* Hs = SB;
  int tid = threadIdx.x;
  int lane = tid & 63, w = tid >> 6;
  int nl = lane & 15, quad = lane >> 4;
  long e0 = (long)blockIdx.x * 64;

  short8 w0f[NC0][2];
  #pragma unroll
  for (int kc = 0; kc < NC0; ++kc)
    #pragma unroll
    for (int ct = 0; ct < 2; ++ct)
      w0f[kc][ct] = ld8(W0t + (long)(w*32 + ct*16 + nl) * K + kc*32 + quad*8);

  #pragma unroll
  for (int it = 0; it < 4; ++it) {
    int i = tid + it * 256;
    int row = i >> 4, col = (i & 15) * 8;
    long eg = e0 + row;
    short8 v = (eg < E) ? ld8(A + eg * 128 + col) : ZERO8;
    *(short8*)&As[row * KP + col] = v;
  }
  #pragma unroll
  for (int it = 0; it < 2; ++it) {
    int i = tid + it * 256;
    int row = i >> 3, col = (i & 7) * 8;
    long eg = e0 + row;
    short8 v = (eg < E) ? ld8(A2 + eg * 64 + col) : ZERO8;
    *(short8*)&As[row * KP + 128 + col] = v;
  }
  __syncthreads();

  // layer 1
  floatx4 acc[4][2];
  #pragma unroll
  for (int i = 0; i < 4; ++i)
    #pragma unroll
    for (int j = 0; j < 2; ++j) acc[i][j] = (floatx4){0.f,0.f,0.f,0.f};
  #pragma unroll
  for (int kc = 0; kc < NC0; ++kc) {
    short8 af[4];
    #pragma unroll
    for (int et = 0; et < 4; ++et)
      af[et] = ld8(&As[(et*16 + nl) * KP + kc*32 + quad*8]);
    #pragma unroll
    for (int et = 0; et < 4; ++et)
      #pragma unroll
      for (int ct = 0; ct < 2; ++ct)
        acc[et][ct] = mfma16(af[et], w0f[kc][ct], acc[et][ct]);
  }

  // preload W1 fragments while waiting
  short8 w1f[4][2];
  #pragma unroll
  for (int kc = 0; kc < 4; ++kc)
    #pragma unroll
    for (int ct = 0; ct < 2; ++ct)
      w1f[kc][ct] = ld8(W1t + (long)(w*32 + ct*16 + nl) * 128 + kc*32 + quad*8);

  __syncthreads();   // all As reads complete before Hs overwrites SB

  #pragma unroll
  for (int et = 0; et < 4; ++et)
    #pragma unroll
    for (int ct = 0; ct < 2; ++ct)
      #pragma unroll
      for (int r = 0; r < 4; ++r)
        Hs[(et*16 + quad*4 + r) * HP + w*32 + ct*16 + nl] =
            f2bu(silu_f(acc[et][ct][r] * scale0));
  __syncthreads();

  // layer 2
  #pragma unroll
  for (int i = 0; i < 4; ++i)
    #pragma unroll
    for (int j = 0; j < 2; ++j) acc[i][j] = (floatx4){0.f,0.f,0.f,0.f};
  #pragma unroll
  for (int kc = 0; kc < 4; ++kc) {
    short8 af[4];
    #pragma unroll
    for (int et = 0; et < 4; ++et)
      af[et] = ld8(&Hs[(et*16 + nl) * HP + kc*32 + quad*8]);
    #pragma unroll
    for (int et = 0; et < 4; ++et)
      #pragma unroll
      for (int ct = 0; ct < 2; ++ct)
        acc[et][ct] = mfma16(af[et], w1f[kc][ct], acc[et][ct]);
  }

  // epilogue: residual into outb (block-private rows -> in-place safe)
  #pragma unroll
  for (int et = 0; et < 4; ++et)
    #pragma unroll
    for (int ct = 0; ct < 2; ++ct)
      #pragma unroll
      for (int r = 0; r < 4; ++r) {
        long eg = e0 + et*16 + quad*4 + r;
        if (eg >= E) continue;
        int col = w*32 + ct*16 + nl;
        float v = acc[et][ct][r] * scale1 * fcut[eg];
        long idx = eg * 128 + col;
        outb[idx] = f2b(C_OLD * b2f(outb[idx]) + C_NEW * v);
      }
}

// ---------------------------------------------------------------------------
// products -> scal0 = [p0 | p1]
// ---------------------------------------------------------------------------
__global__ __launch_bounds__(256) void k_prod(
    const bf16* __restrict__ wedge, const float* __restrict__ env,
    const float* __restrict__ Yb, const int* __restrict__ cent, int E,
    bf16* __restrict__ scal) {
  long t = (long)blockIdx.x * 256 + threadIdx.x;
  if (t >= (long)E * 32) return;
  long e = t >> 5;
  int m = (int)(t & 31);
  int c = cent[e];
  float w0 = b2f(wedge[e*64 + 2*m]), w1 = b2f(wedge[e*64 + 2*m + 1]);
  const float* ep = env + (long)c*128 + m*4;
  float es  = ep[0] * INV_SQRT_N;
  float evx = ep[1] * INV_SQRT_N, evy = ep[2] * INV_SQRT_N, evz = ep[3] * INV_SQRT_N;
  float y1 = Yb[e*4+1], y2 = Yb[e*4+2], y3 = Yb[e*4+3];
  float fvx = w1*y1, fvy = w1*y2, fvz = w1*y3;
  scal[e*64 + m]      = f2b(w0 * es);
  scal[e*64 + 32 + m] = f2b((fvx*evx + fvy*evy + fvz*evz) * INV_SQRT3);
}

// ---------------------------------------------------------------------------
// MFMA mix: products -> LDS, 4 wave-jobs, combine env1 -> scal1
// ---------------------------------------------------------------------------
__global__ __launch_bounds__(256) void k_mix2(
    const bf16* __restrict__ wedge, const float* __restrict__ env,
    const float* __restrict__ env1, const float* __restrict__ Yb,
    const int* __restrict__ cent, const us* __restrict__ Wm,
    int E, bf16* __restrict__ scal) {
  constexpr int PP = 360;
  constexpr int RP = 132;
  __shared__ __align__(16) unsigned char SB[64 * PP * 2];
  __shared__ __align__(16) us Wl[32 * 160];
  us* P = (us*)SB;
  float* R = (float*)SB;
  int tid = threadIdx.x;
  int lane = tid & 63, w = tid >> 6;
  int nl = lane & 15, quad = lane >> 4;
  long e0 = (long)blockIdx.x * 64;

  for (int i = tid; i < 640; i += 256)
    *(short8*)&Wl[i * 8] = ld8(Wm + i * 8);

  int m = tid & 31;
  #pragma unroll
  for (int it = 0; it < 8; ++it) {
    int el = (tid >> 5) + it * 8;
    long e = e0 + el;
    if (e < E) {
      int c = cent[e];
      float w0 = b2f(wedge[e*64 + 2*m]), w1 = b2f(wedge[e*64 + 2*m + 1]);
      float4 ev4 = *(const float4*)(env + (long)c*128 + m*4);
      float4 y   = *(const float4*)(Yb + e*4);
      float es  = ev4.x * INV_SQRT_N;
      float evx = ev4.y * INV_SQRT_N, evy = ev4.z * INV_SQRT_N, evz = ev4.w * INV_SQRT_N;
      float fvx = w1*y.y, fvy = w1*y.z, fvz = w1*y.w;
      us* p = P + el * PP;
      p[m]       = f2bu(w0 * es);
      p[32 + m]  = f2bu((fvx*evx + fvy*evy + fvz*evz) * INV_SQRT3);
      p[64 + m]  = f2bu(w0 * evx);
      p[96 + m]  = f2bu(fvx * es);
      p[128 + m] = f2bu((fvy*evz - fvz*evy) * INV_SQRT2);
      p[160 + m] = f2bu(w0 * evy);
      p[192 + m] = f2bu(fvy * es);
      p[224 + m] = f2bu((fvz*evx - fvx*evz) * INV_SQRT2);
      p[256 + m] = f2bu(w0 * evz);
      p[288 + m] = f2bu(fvz * es);
      p[320 + m] = f2bu((fvx*evy - fvy*evx) * INV_SQRT2);
    } else {
      us* p = P + el * PP;
      #pragma unroll
      for (int q = 0; q < 11; ++q) p[q*32 + m] = 0;
    }
  }
  __syncthreads();

  floatx4 acc[4][2];
  #pragma unroll
  for (int i = 0; i < 4; ++i)
    #pragma unroll
    for (int j = 0; j < 2; ++j) acc[i][j] = (floatx4){0.f,0.f,0.f,0.f};
  int pbase  = (w == 0) ? 0 : 64 + (w - 1) * 96;
  int wkbase = (w == 0) ? 0 : 64;
  int ksteps = (w == 0) ? 2 : 3;
  for (int ks = 0; ks < ksteps; ++ks) {
    short8 af[4], bv[2];
    #pragma unroll
    for (int et = 0; et < 4; ++et)
      af[et] = ld8(&P[(et*16 + nl) * PP + pbase + ks*32 + quad*8]);
    #pragma unroll
    for (int ct = 0; ct < 2; ++ct)
      bv[ct] = ld8(&Wl[(ct*16 + nl) * 160 + wkbase + ks*32 + quad*8]);
    #pragma unroll
    for (int et = 0; et < 4; ++et)
      #pragma unroll
      for (int ct = 0; ct < 2; ++ct)
        acc[et][ct] = mfma16(af[et], bv[ct], acc[et][ct]);
  }
  __syncthreads();

  #pragma unroll
  for (int et = 0; et < 4; ++et)
    #pragma unroll
    for (int ct = 0; ct < 2; ++ct)
      #pragma unroll
      for (int r = 0; r < 4; ++r) {
        int el = et*16 + quad*4 + r;
        R[el * RP + w*32 + ct*16 + nl] = acc[et][ct][r];
      }
  __syncthreads();

  #pragma unroll
  for (int it = 0; it < 8; ++it) {
    int el = (tid >> 5) + it * 8;
    long e = e0 + el;
    if (e >= E) continue;
    int o = m;
    int c = cent[e];
    float4 e1 = *(const float4*)(env1 + (long)c*128 + o*4);
    float sr = R[el * RP + o];
    float vx = R[el * RP + 32 + o];
    float vy = R[el * RP + 64 + o];
    float vz = R[el * RP + 96 + o];
    float q0 = sr * 0.125f * (e1.x * INV_SQRT_N);
    float q1 = (vx*e1.y + vy*e1.z + vz*e1.w) *
               (0.10206207261596577f * INV_SQRT_N * INV_SQRT3);
    scal[e*64 + o]      = f2b(q0);
    scal[e*64 + 32 + o] = f2b(q1);
  }
}

// ---------------------------------------------------------------------------
extern "C" void kernel_launch(void* const* d_in, const int* in_sizes, int n_in,
                              void* d_out, int out_size, void* d_ws, size_t ws_size,
                              hipStream_t stream) {
  const float* coords = (const float*)d_in[0];
  const float* nattr  = (const float*)d_in[1];
  const int*   eidx   = (const int*)d_in[2];
  const float* W2b0   = (const float*)d_in[3];
  const float* W2b1   = (const float*)d_in[4];
  const float* W2b2   = (const float*)d_in[5];
  const float* Wenv0  = (const float*)d_in[6];
  const float* Wlat0  = (const float*)d_in[7];
  const float* Wlat1  = (const float*)d_in[8];
  const float* Ws0    = (const float*)d_in[9];
  const float* Wv0    = (const float*)d_in[10];
  const float* Wenv1  = (const float*)d_in[11];
  const float* Wfin0  = (const float*)d_in[12];
  const float* Wfin1  = (const float*)d_in[13];
  float* out = (float*)d_out;
  int E = in_sizes[2] / 2;     // 320000
  int N = in_sizes[0] / 3;     // 10000

  // workspace carve (~183 MB)
  float* fcut   = (float*)d_ws;                    // E
  float* Yb     = fcut + (size_t)E;                // 4E
  float* env    = Yb + (size_t)E*4;                // 128N
  float* env1   = env + (size_t)N*128;             // 128N
  int*   deg    = (int*)(env1 + (size_t)N*128);    // N
  int*   rowptr = deg + N;                         // N+8
  int*   cursor = rowptr + (N + 8);                // N
  int*   eord   = cursor + N;                      // E
  int*   cent   = eord + E;                        // E
  bf16*  b64    = (bf16*)(cent + E);               // 64E (wedge)
  bf16*  lat    = b64 + (size_t)E*64;              // 128E
  bf16*  S      = lat + (size_t)E*128;             // 64E (a64/wenv/scal0/wenv1/scal1)
  us* W2b1t  = (us*)(S + (size_t)E*64);            // 128x64
  us* W2b2t  = W2b1t + 128*64;                     // 128x128
  us* Wenv0t = W2b2t + 128*128;                    // 128x128
  us* Wlat0t = Wenv0t + 128*128;                   // 128x192
  us* Wlat1t = Wlat0t + 128*192;                   // 128x128
  us* Wenv1t = Wlat1t + 128*128;                   // 64x128
  us* Wfin0t = Wenv1t + 64*128;                    // 128x192
  us* Wfin1t = Wfin0t + 128*192;                   // 128x128
  us* W2b0p  = Wfin1t + 128*128;                   // 64x64 (zero-padded)
  us* Wmixt  = W2b0p + 64*64;                      // 32x160

  hipMemsetAsync(deg, 0, (size_t)N * sizeof(int), stream);

  dim3 blk(256);
  const float s40  = 0.15811388300841897f;  // 1/sqrt(40)
  const float s64  = 0.125f;
  const float s128 = 0.08838834764831845f;
  const float s192 = 0.07216878364870323f;
  int gB = (E + 63) / 64;
  int gE = (E + 255) / 256;

  // CSR build, slot-ordered geometry, merged weight prep
  k_deg<<<gE, blk, 0, stream>>>(eidx, E, deg);
  k_scan<<<1, 1024, 0, stream>>>(deg, N, rowptr, cursor);
  k_fill<<<gE, blk, 0, stream>>>(eidx, E, cursor, eord, cent);
  k_geom<<<gE, blk, 0, stream>>>(coords, nattr, eidx, eord, E, fcut, Yb, S /*a64*/);
  k_wprep_all<<<dim3(548), blk, 0, stream>>>(
      W2b0, W2b1, W2b2, Wenv0, Wlat0, Wlat1, Wenv1, Wfin0, Wfin1, Ws0, Wv0,
      W2b0p, W2b1t, W2b2t, Wenv0t, Wlat0t, Wlat1t, Wenv1t, Wfin0t, Wfin1t, Wmixt);

  // two-body MLP (3 layers fused) -> lat
  mfused3<<<gB, blk, 0, stream>>>(
      S /*a64*/, W2b0p, W2b1t, W2b2t, lat, fcut, s40, s64, s128, E);

  // Wenv0: w_edge -> b64, w_env -> S
  mgemm<128,EPI_SPLIT><<<gB, blk, 0, stream>>>(
      lat, Wenv0t, b64, S /*wenv*/, s128, E);

  // env = CSR gather
  k_envg<<<dim3((N*32 + 255) / 256), blk, 0, stream>>>(
      S /*wenv*/, Yb, rowptr, N, env);

  // products -> scal0
  k_prod<<<dim3((int)(((long)E*32 + 255) / 256)), blk, 0, stream>>>(
      b64, env, Yb, cent, E, S /*scal0*/);

  // latent MLP + residual
  mfused<EPI_RESID><<<gB, blk, 0, stream>>>(
      lat, S /*scal0*/, Wlat0t, Wlat1t, lat, fcut, s192, s128, E);

  // Wenv1 -> wenv1
  mgemm<64,EPI_STORE><<<gB, blk, 0, stream>>>(
      lat, Wenv1t, S /*wenv1*/, nullptr, s128, E);

  // env1 = CSR gather
  k_envg<<<dim3((N*32 + 255) / 256), blk, 0, stream>>>(
      S /*wenv1*/, Yb, rowptr, N, env1);

  // MFMA mix -> scal1
  k_mix2<<<gB, blk, 0, stream>>>(
      b64, env, env1, Yb, cent, Wmixt, E, S /*scal1*/);

  // final MLP + residual
  mfused<EPI_RESID><<<gB, blk, 0, stream>>>(
      lat, S /*scal1*/, Wfin0t, Wfin1t, lat, fcut, s192, s128, E);

  // node segment-sum -> d_out
  k_nodeg<<<dim3((N*128 + 255) / 256), blk, 0, stream>>>(
      lat, rowptr, N, out);
}

// Round 13
// 722.707 us; speedup vs baseline: 1.0675x; 1.0675x over previous
//
#include <hip/hip_runtime.h>
#include <hip/hip_bf16.h>
#include <math.h>

typedef __hip_bfloat16 bf16;
typedef unsigned short us;
typedef __attribute__((ext_vector_type(8))) short short8;
typedef __attribute__((ext_vector_type(4))) float floatx4;

#define INV_SQRT_N 0.17677669529663687f   /* 1/sqrt(32) */
#define INV_SQRT3  0.5773502691896258f
#define INV_SQRT2  0.7071067811865476f
#define C_OLD      0.8944271909999159f    /* 1/sqrt(1.25) */
#define C_NEW      0.4472135954999579f
#define PI_F       3.14159265358979323846f
#define SQRT3_F    1.7320508075688772f
#define BESSEL_PREF 0.6324555320336759f   /* sqrt(2/5) */

__device__ __forceinline__ float b2f(bf16 x) { return __bfloat162float(x); }
__device__ __forceinline__ bf16  f2b(float x) { return __float2bfloat16(x); }
__device__ __forceinline__ us f2bu(float x) {
  bf16 h = f2b(x); us u; __builtin_memcpy(&u, &h, 2); return u;
}
__device__ __forceinline__ float bu2f(us u) {
  bf16 h; __builtin_memcpy(&h, &u, 2); return b2f(h);
}
__device__ __forceinline__ float silu_f(float v) { return v / (1.f + __expf(-v)); }
__device__ __forceinline__ floatx4 mfma16(short8 a, short8 b, floatx4 c) {
  return __builtin_amdgcn_mfma_f32_16x16x32_bf16(a, b, c, 0, 0, 0);
}
__device__ __forceinline__ short8 ld8(const void* p) {
  return *reinterpret_cast<const short8*>(p);
}
#define ZERO8 ((short8){0,0,0,0,0,0,0,0})

// ---------------------------------------------------------------------------
// CSR build
// ---------------------------------------------------------------------------
__global__ __launch_bounds__(256) void k_deg(
    const int* __restrict__ eidx, int E, int* __restrict__ deg) {
  int e = blockIdx.x * 256 + threadIdx.x;
  if (e < E) atomicAdd(&deg[eidx[E + e]], 1);
}

__global__ __launch_bounds__(1024) void k_scan(
    const int* __restrict__ deg, int N,
    int* __restrict__ rowptr, int* __restrict__ cursor) {
  __shared__ int part[1024];
  int t = threadIdx.x;
  int C = (N + 1023) / 1024;
  int base = t * C;
  int s = 0;
  for (int i = 0; i < C; ++i) { int idx = base + i; if (idx < N) s += deg[idx]; }
  part[t] = s;
  __syncthreads();
  for (int off = 1; off < 1024; off <<= 1) {
    int v = (t >= off) ? part[t - off] : 0;
    __syncthreads();
    part[t] += v;
    __syncthreads();
  }
  int excl = (t == 0) ? 0 : part[t - 1];
  for (int i = 0; i < C; ++i) {
    int idx = base + i;
    if (idx < N) { rowptr[idx] = excl; cursor[idx] = excl; excl += deg[idx]; }
  }
  if (t == 0) rowptr[N] = part[1023];
}

__global__ __launch_bounds__(256) void k_fill(
    const int* __restrict__ eidx, int E, int* __restrict__ cursor,
    int* __restrict__ eord, int* __restrict__ cent) {
  int e = blockIdx.x * 256 + threadIdx.x;
  if (e >= E) return;
  int c = eidx[E + e];
  int slot = atomicAdd(&cursor[c], 1);
  eord[slot] = e;
  cent[slot] = c;
}

// ---------------------------------------------------------------------------
// per-slot geometry + A64 row build: [nattr[c](16)|nattr[s](16)|ef(8)|0(24)]
// ---------------------------------------------------------------------------
__global__ __launch_bounds__(256) void k_geom(
    const float* __restrict__ coords, const float* __restrict__ nattr,
    const int* __restrict__ eidx, const int* __restrict__ eord, int E,
    float* __restrict__ fcut, float* __restrict__ Yb, bf16* __restrict__ a64) {
  int j = blockIdx.x * 256 + threadIdx.x;
  if (j >= E) return;
  int e = eord[j];
  int s = eidx[e], c = eidx[E + e];
  float dx = coords[c*3+0] - coords[s*3+0];
  float dy = coords[c*3+1] - coords[s*3+1];
  float dz = coords[c*3+2] - coords[s*3+2];
  float r = sqrtf(dx*dx + dy*dy + dz*dz + 1e-12f);
  float u = r * 0.2f;
  float u3 = u*u*u;
  float u6 = u3*u3, u7 = u6*u, u8 = u7*u;
  float fc = 1.f - 28.f*u6 + 48.f*u7 - 21.f*u8;
  fc = (u < 1.f) ? fc : 0.f;
  float inv_r = 1.f / r;
  fcut[j] = fc;
  Yb[j*4+0] = 1.f;
  Yb[j*4+1] = SQRT3_F * dx * inv_r;
  Yb[j*4+2] = SQRT3_F * dy * inv_r;
  Yb[j*4+3] = SQRT3_F * dz * inv_r;
  bf16* row = a64 + (long)j * 64;
  #pragma unroll
  for (int i = 0; i < 16; ++i) row[i]      = f2b(nattr[(long)c*16 + i]);
  #pragma unroll
  for (int i = 0; i < 16; ++i) row[16 + i] = f2b(nattr[(long)s*16 + i]);
  float pref = BESSEL_PREF * inv_r * fc;
  #pragma unroll
  for (int n = 1; n <= 8; ++n)
    row[32 + n - 1] = f2b(pref * sinf((float)n * PI_F * u));
  #pragma unroll
  for (int i = 40; i < 64; ++i) row[i] = f2b(0.f);
}

// ---------------------------------------------------------------------------
// merged weight prep: fp32 W[k][n] -> bf16 Wt[n][k]; W2b0 padded to 64x64.
// ---------------------------------------------------------------------------
__device__ __forceinline__ void wp(const float* W, us* Wt, int K, int NOUT, int t) {
  int n = t / K, k = t % K;
  Wt[n * K + k] = f2bu(W[k * NOUT + n]);
}

__global__ __launch_bounds__(256) void k_wprep_all(
    const float* W2b0, const float* W2b1, const float* W2b2,
    const float* Wenv0, const float* Wlat0, const float* Wlat1,
    const float* Wenv1, const float* Wfin0, const float* Wfin1,
    const float* Ws0, const float* Wv0,
    us* W2b0p, us* W2b1t, us* W2b2t, us* Wenv0t, us* Wlat0t, us* Wlat1t,
    us* Wenv1t, us* Wfin0t, us* Wfin1t, us* Wmixt) {
  int t = blockIdx.x * 256 + threadIdx.x;
  if (t < 8192)  { wp(W2b1,  W2b1t,  64, 128, t); return; } t -= 8192;
  if (t < 16384) { wp(W2b2,  W2b2t, 128, 128, t); return; } t -= 16384;
  if (t < 16384) { wp(Wenv0, Wenv0t,128, 128, t); return; } t -= 16384;
  if (t < 24576) { wp(Wlat0, Wlat0t,192, 128, t); return; } t -= 24576;
  if (t < 16384) { wp(Wlat1, Wlat1t,128, 128, t); return; } t -= 16384;
  if (t < 8192)  { wp(Wenv1, Wenv1t,128,  64, t); return; } t -= 8192;
  if (t < 24576) { wp(Wfin0, Wfin0t,192, 128, t); return; } t -= 24576;
  if (t < 16384) { wp(Wfin1, Wfin1t,128, 128, t); return; } t -= 16384;
  if (t < 4096)  {
    int n = t >> 6, k = t & 63;
    W2b0p[n * 64 + k] = (k < 40) ? f2bu(W2b0[k * 64 + n]) : 0;
    return;
  } t -= 4096;
  if (t < 5120) {
    int o = t / 160, k = t % 160;
    float v = (k < 64) ? Ws0[k * 32 + o] : Wv0[(k - 64) * 32 + o];
    Wmixt[o * 160 + k] = f2bu(v);
  }
}

// ---------------------------------------------------------------------------
// env gather + scal0 products fused (CSR, slot-ordered).
// Phase 1: env[n][m][:] = sum over slots; Phase 2: per-edge p0/p1 -> scal0.
// ---------------------------------------------------------------------------
__global__ __launch_bounds__(256) void k_envgp(
    const bf16* __restrict__ wenv, const bf16* __restrict__ wedge,
    const float* __restrict__ Yb, const int* __restrict__ rowptr,
    int N, float* __restrict__ env, bf16* __restrict__ scal) {
  int t = blockIdx.x * 256 + threadIdx.x;
  if (t >= N * 32) return;
  int n = t >> 5, m = t & 31;
  int j0 = rowptr[n], j1 = rowptr[n + 1];
  float a0 = 0.f, a1 = 0.f, a2 = 0.f, a3 = 0.f;
  for (int j = j0; j < j1; ++j) {
    float w0 = b2f(wenv[(long)j*64 + 2*m]);
    float w1 = b2f(wenv[(long)j*64 + 2*m + 1]);
    float4 y = *reinterpret_cast<const float4*>(&Yb[(long)j*4]);
    a0 += w0;
    a1 += w1 * y.y;
    a2 += w1 * y.z;
    a3 += w1 * y.w;
  }
  *reinterpret_cast<float4*>(&env[(long)n*128 + m*4]) = make_float4(a0, a1, a2, a3);
  float es  = a0 * INV_SQRT_N;
  float evx = a1 * INV_SQRT_N, evy = a2 * INV_SQRT_N, evz = a3 * INV_SQRT_N;
  for (int j = j0; j < j1; ++j) {
    float w0 = b2f(wedge[(long)j*64 + 2*m]);
    float w1 = b2f(wedge[(long)j*64 + 2*m + 1]);
    float4 y = *reinterpret_cast<const float4*>(&Yb[(long)j*4]);
    float fvx = w1*y.y, fvy = w1*y.z, fvz = w1*y.w;
    scal[(long)j*64 + m]      = f2b(w0 * es);
    scal[(long)j*64 + 32 + m] = f2b((fvx*evx + fvy*evy + fvz*evz) * INV_SQRT3);
  }
}

// ---------------------------------------------------------------------------
// env gather only (CSR, slot-ordered) - for env1
// ---------------------------------------------------------------------------
__global__ __launch_bounds__(256) void k_envg(
    const bf16* __restrict__ wenv, const float* __restrict__ Yb,
    const int* __restrict__ rowptr, int N, float* __restrict__ env) {
  int t = blockIdx.x * 256 + threadIdx.x;
  if (t >= N * 32) return;
  int n = t >> 5, m = t & 31;
  int j0 = rowptr[n], j1 = rowptr[n + 1];
  float a0 = 0.f, a1 = 0.f, a2 = 0.f, a3 = 0.f;
  for (int j = j0; j < j1; ++j) {
    float w0 = b2f(wenv[(long)j*64 + 2*m]);
    float w1 = b2f(wenv[(long)j*64 + 2*m + 1]);
    float4 y = *reinterpret_cast<const float4*>(&Yb[(long)j*4]);
    a0 += w0;
    a1 += w1 * y.y;
    a2 += w1 * y.z;
    a3 += w1 * y.w;
  }
  *reinterpret_cast<float4*>(&env[(long)n*128 + m*4]) = make_float4(a0, a1, a2, a3);
}

// ---------------------------------------------------------------------------
// node gather (CSR, slot-ordered) -> d_out
// ---------------------------------------------------------------------------
__global__ __launch_bounds__(256) void k_nodeg(
    const bf16* __restrict__ lat, const int* __restrict__ rowptr,
    int N, float* __restrict__ out) {
  int t = blockIdx.x * 256 + threadIdx.x;
  if (t >= N * 128) return;
  int n = t >> 7, j = t & 127;
  int j0 = rowptr[n], j1 = rowptr[n + 1];
  float s = 0.f;
  for (int q = j0; q < j1; ++q)
    s += b2f(lat[(long)q*128 + j]);
  out[t] = s * INV_SQRT_N;
}

// ---------------------------------------------------------------------------
// mfused3s: a64(40p) ->silu 64 ->silu 128 ->128*fcut = lat,
// then tail GEMM lat@Wenv0 -> split b64(w_edge) / wenv.
// ---------------------------------------------------------------------------
__global__ __launch_bounds__(256) void mfused3s(
    const bf16* __restrict__ a64, const us* __restrict__ W0p,
    const us* __restrict__ W1t, const us* __restrict__ W2t,
    const us* __restrict__ Wenv0t,
    bf16* __restrict__ lat, bf16* __restrict__ b64, bf16* __restrict__ wenv,
    const float* __restrict__ fcut,
    float s40, float s64s, float s128, int E) {
  constexpr int AP = 72, HP = 136;
  __shared__ __align__(16) us SB[64 * 144];   // As | H0 ; Hs aliases whole
  us* As = SB;
  us* H0 = SB + 64 * AP;
  us* Hs = SB;
  int tid = threadIdx.x;
  int lane = tid & 63, w = tid >> 6;
  int nl = lane & 15, quad = lane >> 4;
  long e0 = (long)blockIdx.x * 64;

  short8 w0f[2], w1f[2][2], w2f[4][2];
  #pragma unroll
  for (int kc = 0; kc < 2; ++kc)
    w0f[kc] = ld8(W0p + (w*16 + nl) * 64 + kc*32 + quad*8);
  #pragma unroll
  for (int kc = 0; kc < 2; ++kc)
    #pragma unroll
    for (int ct = 0; ct < 2; ++ct)
      w1f[kc][ct] = ld8(W1t + (long)(w*32 + ct*16 + nl) * 64 + kc*32 + quad*8);
  #pragma unroll
  for (int kc = 0; kc < 4; ++kc)
    #pragma unroll
    for (int ct = 0; ct < 2; ++ct)
      w2f[kc][ct] = ld8(W2t + (long)(w*32 + ct*16 + nl) * 128 + kc*32 + quad*8);

  #pragma unroll
  for (int it = 0; it < 2; ++it) {
    int i = tid + it * 256;
    int row = i >> 3, col = (i & 7) * 8;
    long eg = e0 + row;
    short8 v = (eg < E) ? ld8(a64 + eg * 64 + col) : ZERO8;
    *(short8*)&As[row * AP + col] = v;
  }
  __syncthreads();

  // layer 0: 64(40p) -> 64, silu -> H0
  floatx4 a0[4];
  #pragma unroll
  for (int i = 0; i < 4; ++i) a0[i] = (floatx4){0.f,0.f,0.f,0.f};
  #pragma unroll
  for (int kc = 0; kc < 2; ++kc) {
    short8 af[4];
    #pragma unroll
    for (int et = 0; et < 4; ++et)
      af[et] = ld8(&As[(et*16 + nl) * AP + kc*32 + quad*8]);
    #pragma unroll
    for (int et = 0; et < 4; ++et) a0[et] = mfma16(af[et], w0f[kc], a0[et]);
  }
  #pragma unroll
  for (int et = 0; et < 4; ++et)
    #pragma unroll
    for (int r = 0; r < 4; ++r)
      H0[(et*16 + quad*4 + r) * AP + w*16 + nl] = f2bu(silu_f(a0[et][r] * s40));
  __syncthreads();

  // layer 1: 64 -> 128, silu (regs)
  floatx4 acc[4][2];
  #pragma unroll
  for (int i = 0; i < 4; ++i)
    #pragma unroll
    for (int j = 0; j < 2; ++j) acc[i][j] = (floatx4){0.f,0.f,0.f,0.f};
  #pragma unroll
  for (int kc = 0; kc < 2; ++kc) {
    short8 af[4];
    #pragma unroll
    for (int et = 0; et < 4; ++et)
      af[et] = ld8(&H0[(et*16 + nl) * AP + kc*32 + quad*8]);
    #pragma unroll
    for (int et = 0; et < 4; ++et)
      #pragma unroll
      for (int ct = 0; ct < 2; ++ct)
        acc[et][ct] = mfma16(af[et], w1f[kc][ct], acc[et][ct]);
  }
  __syncthreads();   // H0 reads done before Hs overwrite

  #pragma unroll
  for (int et = 0; et < 4; ++et)
    #pragma unroll
    for (int ct = 0; ct < 2; ++ct)
      #pragma unroll
      for (int r = 0; r < 4; ++r)
        Hs[(et*16 + quad*4 + r) * HP + w*32 + ct*16 + nl] =
            f2bu(silu_f(acc[et][ct][r] * s64s));
  __syncthreads();

  // layer 2: 128 -> 128, *fcut -> lat (global) and latf kept in regs
  #pragma unroll
  for (int i = 0; i < 4; ++i)
    #pragma unroll
    for (int j = 0; j < 2; ++j) acc[i][j] = (floatx4){0.f,0.f,0.f,0.f};
  #pragma unroll
  for (int kc = 0; kc < 4; ++kc) {
    short8 af[4];
    #pragma unroll
    for (int et = 0; et < 4; ++et)
      af[et] = ld8(&Hs[(et*16 + nl) * HP + kc*32 + quad*8]);
    #pragma unroll
    for (int et = 0; et < 4; ++et)
      #pragma unroll
      for (int ct = 0; ct < 2; ++ct)
        acc[et][ct] = mfma16(af[et], w2f[kc][ct], acc[et][ct]);
  }

  // preload tail W frags (w0f/w1f/w2f dead now)
  short8 wef[4][2];
  #pragma unroll
  for (int kc = 0; kc < 4; ++kc)
    #pragma unroll
    for (int ct = 0; ct < 2; ++ct)
      wef[kc][ct] = ld8(Wenv0t + (long)(w*32 + ct*16 + nl) * 128 + kc*32 + quad*8);

  __syncthreads();   // Hs (layer-2 source) reads done before latf overwrite

  #pragma unroll
  for (int et = 0; et < 4; ++et)
    #pragma unroll
    for (int ct = 0; ct < 2; ++ct)
      #pragma unroll
      for (int r = 0; r < 4; ++r) {
        long eg = e0 + et*16 + quad*4 + r;
        int col = w*32 + ct*16 + nl;
        us lv = 0;
        if (eg < E) {
          lv = f2bu(acc[et][ct][r] * s128 * fcut[eg]);
          lat[eg * 128 + col] = f2b(bu2f(lv));
        }
        Hs[(et*16 + quad*4 + r) * HP + col] = lv;
      }
  __syncthreads();

  // tail GEMM: latf(128) @ Wenv0 -> 128, split
  #pragma unroll
  for (int i = 0; i < 4; ++i)
    #pragma unroll
    for (int j = 0; j < 2; ++j) acc[i][j] = (floatx4){0.f,0.f,0.f,0.f};
  #pragma unroll
  for (int kc = 0; kc < 4; ++kc) {
    short8 af[4];
    #pragma unroll
    for (int et = 0; et < 4; ++et)
      af[et] = ld8(&Hs[(et*16 + nl) * HP + kc*32 + quad*8]);
    #pragma unroll
    for (int et = 0; et < 4; ++et)
      #pragma unroll
      for (int ct = 0; ct < 2; ++ct)
        acc[et][ct] = mfma16(af[et], wef[kc][ct], acc[et][ct]);
  }
  #pragma unroll
  for (int et = 0; et < 4; ++et)
    #pragma unroll
    for (int ct = 0; ct < 2; ++ct)
      #pragma unroll
      for (int r = 0; r < 4; ++r) {
        long eg = e0 + et*16 + quad*4 + r;
        if (eg >= E) continue;
        int col = w*32 + ct*16 + nl;
        float v = acc[et][ct][r] * s128;
        if (col < 64) b64[eg * 64 + col] = f2b(v);
        else          wenv[eg * 64 + (col - 64)] = f2b(v);
      }
}

// ---------------------------------------------------------------------------
// mfuseds: [lat|scal] ->silu 128 ->128, residual into lat, then tail GEMM
// newlat@Wenv1 -> wenv1 (64 cols). HAS_TAIL=0 gives the plain final MLP.
// ---------------------------------------------------------------------------
template<int HAS_TAIL>
__global__ __launch_bounds__(256) void mfuseds(
    const bf16* __restrict__ A, const bf16* __restrict__ A2,
    const us* __restrict__ W0t, const us* __restrict__ W1t,
    const us* __restrict__ Wenv1t,
    bf16* __restrict__ outb, bf16* __restrict__ wenv1,
    const float* __restrict__ fcut,
    float scale0, float scale1, int E) {
  constexpr int K = 192, KP = 200, NC0 = 6, HP = 136;
  __shared__ __align__(16) us SB[64 * KP];   // As stride-200; Hs stride-136 alias
  us* As = SB;
  us* Hs = SB;
  int tid = threadIdx.x;
  int lane = tid & 63, w = tid >> 6;
  int nl = lane & 15, quad = lane >> 4;
  long e0 = (long)blockIdx.x * 64;

  short8 w0f[NC0][2];
  #pragma unroll
  for (int kc = 0; kc < NC0; ++kc)
    #pragma unroll
    for (int ct = 0; ct < 2; ++ct)
      w0f[kc][ct] = ld8(W0t + (long)(w*32 + ct*16 + nl) * K + kc*32 + quad*8);

  #pragma unroll
  for (int it = 0; it < 4; ++it) {
    int i = tid + it * 256;
    int row = i >> 4, col = (i & 15) * 8;
    long eg = e0 + row;
    short8 v = (eg < E) ? ld8(A + eg * 128 + col) : ZERO8;
    *(short8*)&As[row * KP + col] = v;
  }
  #pragma unroll
  for (int it = 0; it < 2; ++it) {
    int i = tid + it * 256;
    int row = i >> 3, col = (i & 7) * 8;
    long eg = e0 + row;
    short8 v = (eg < E) ? ld8(A2 + eg * 64 + col) : ZERO8;
    *(short8*)&As[row * KP + 128 + col] = v;
  }
  __syncthreads();

  // layer 1
  floatx4 acc[4][2];
  #pragma unroll
  for (int i = 0; i < 4; ++i)
    #pragma unroll
    for (int j = 0; j < 2; ++j) acc[i][j] = (floatx4){0.f,0.f,0.f,0.f};
  #pragma unroll
  for (int kc = 0; kc < NC0; ++kc) {
    short8 af[4];
    #pragma unroll
    for (int et = 0; et < 4; ++et)
      af[et] = ld8(&As[(et*16 + nl) * KP + kc*32 + quad*8]);
    #pragma unroll
    for (int et = 0; et < 4; ++et)
      #pragma unroll
      for (int ct = 0; ct < 2; ++ct)
        acc[et][ct] = mfma16(af[et], w0f[kc][ct], acc[et][ct]);
  }

  short8 w1f[4][2];
  #pragma unroll
  for (int kc = 0; kc < 4; ++kc)
    #pragma unroll
    for (int ct = 0; ct < 2; ++ct)
      w1f[kc][ct] = ld8(W1t + (long)(w*32 + ct*16 + nl) * 128 + kc*32 + quad*8);

  __syncthreads();   // As reads done before Hs overwrite

  #pragma unroll
  for (int et = 0; et < 4; ++et)
    #pragma unroll
    for (int ct = 0; ct < 2; ++ct)
      #pragma unroll
      for (int r = 0; r < 4; ++r)
        Hs[(et*16 + quad*4 + r) * HP + w*32 + ct*16 + nl] =
            f2bu(silu_f(acc[et][ct][r] * scale0));
  __syncthreads();

  // layer 2
  #pragma unroll
  for (int i = 0; i < 4; ++i)
    #pragma unroll
    for (int j = 0; j < 2; ++j) acc[i][j] = (floatx4){0.f,0.f,0.f,0.f};
  #pragma unroll
  for (int kc = 0; kc < 4; ++kc) {
    short8 af[4];
    #pragma unroll
    for (int et = 0; et < 4; ++et)
      af[et] = ld8(&Hs[(et*16 + nl) * HP + kc*32 + quad*8]);
    #pragma unroll
    for (int et = 0; et < 4; ++et)
      #pragma unroll
      for (int ct = 0; ct < 2; ++ct)
        acc[et][ct] = mfma16(af[et], w1f[kc][ct], acc[et][ct]);
  }

  if constexpr (!HAS_TAIL) {
    #pragma unroll
    for (int et = 0; et < 4; ++et)
      #pragma unroll
      for (int ct = 0; ct < 2; ++ct)
        #pragma unroll
        for (int r = 0; r < 4; ++r) {
          long eg = e0 + et*16 + quad*4 + r;
          if (eg >= E) continue;
          int col = w*32 + ct*16 + nl;
          float v = acc[et][ct][r] * scale1 * fcut[eg];
          long idx = eg * 128 + col;
          outb[idx] = f2b(C_OLD * b2f(outb[idx]) + C_NEW * v);
        }
  } else {
    // residual + keep newlat; stash into Hs for tail GEMM
    short8 wef[4];
    #pragma unroll
    for (int kc = 0; kc < 4; ++kc)
      wef[kc] = ld8(Wenv1t + (long)(w*16 + nl) * 128 + kc*32 + quad*8);

    __syncthreads();   // layer-2 Hs reads done before overwrite

    #pragma unroll
    for (int et = 0; et < 4; ++et)
      #pragma unroll
      for (int ct = 0; ct < 2; ++ct)
        #pragma unroll
        for (int r = 0; r < 4; ++r) {
          long eg = e0 + et*16 + quad*4 + r;
          int col = w*32 + ct*16 + nl;
          us lv = 0;
          if (eg < E) {
            float v = acc[et][ct][r] * scale1 * fcut[eg];
            long idx = eg * 128 + col;
            lv = f2bu(C_OLD * b2f(outb[idx]) + C_NEW * v);
            outb[idx] = f2b(bu2f(lv));
          }
          Hs[(et*16 + quad*4 + r) * HP + col] = lv;
        }
    __syncthreads();

    // tail: newlat(128) @ Wenv1 -> 64 cols; wave w covers cols w*16..w*16+15
    floatx4 acc2[4];
    #pragma unroll
    for (int i = 0; i < 4; ++i) acc2[i] = (floatx4){0.f,0.f,0.f,0.f};
    #pragma unroll
    for (int kc = 0; kc < 4; ++kc) {
      short8 af[4];
      #pragma unroll
      for (int et = 0; et < 4; ++et)
        af[et] = ld8(&Hs[(et*16 + nl) * HP + kc*32 + quad*8]);
      #pragma unroll
      for (int et = 0; et < 4; ++et)
        acc2[et] = mfma16(af[et], wef[kc], acc2[et]);
    }
    #pragma unroll
    for (int et = 0; et < 4; ++et)
      #pragma unroll
      for (int r = 0; r < 4; ++r) {
        long eg = e0 + et*16 + quad*4 + r;
        if (eg >= E) continue;
        wenv1[eg * 64 + w*16 + nl] = f2b(acc2[et][r] * 0.08838834764831845f);
      }
  }
}

// ---------------------------------------------------------------------------
// MFMA mix: products -> LDS, 4 wave-jobs, combine env1 -> scal1
// ---------------------------------------------------------------------------
__global__ __launch_bounds__(256) void k_mix2(
    const bf16* __restrict__ wedge, const float* __restrict__ env,
    const float* __restrict__ env1, const float* __restrict__ Yb,
    const int* __restrict__ cent, const us* __restrict__ Wm,
    int E, bf16* __restrict__ scal) {
  constexpr int PP = 360;
  constexpr int RP = 132;
  __shared__ __align__(16) unsigned char SB[64 * PP * 2];
  __shared__ __align__(16) us Wl[32 * 160];
  us* P = (us*)SB;
  float* R = (float*)SB;
  int tid = threadIdx.x;
  int lane = tid & 63, w = tid >> 6;
  int nl = lane & 15, quad = lane >> 4;
  long e0 = (long)blockIdx.x * 64;

  for (int i = tid; i < 640; i += 256)
    *(short8*)&Wl[i * 8] = ld8(Wm + i * 8);

  int m = tid & 31;
  #pragma unroll
  for (int it = 0; it < 8; ++it) {
    int el = (tid >> 5) + it * 8;
    long e = e0 + el;
    if (e < E) {
      int c = cent[e];
      float w0 = b2f(wedge[e*64 + 2*m]), w1 = b2f(wedge[e*64 + 2*m + 1]);
      float4 ev4 = *(const float4*)(env + (long)c*128 + m*4);
      float4 y   = *(const float4*)(Yb + e*4);
      float es  = ev4.x * INV_SQRT_N;
      float evx = ev4.y * INV_SQRT_N, evy = ev4.z * INV_SQRT_N, evz = ev4.w * INV_SQRT_N;
      float fvx = w1*y.y, fvy = w1*y.z, fvz = w1*y.w;
      us* p = P + el * PP;
      p[m]       = f2bu(w0 * es);
      p[32 + m]  = f2bu((fvx*evx + fvy*evy + fvz*evz) * INV_SQRT3);
      p[64 + m]  = f2bu(w0 * evx);
      p[96 + m]  = f2bu(fvx * es);
      p[128 + m] = f2bu((fvy*evz - fvz*evy) * INV_SQRT2);
      p[160 + m] = f2bu(w0 * evy);
      p[192 + m] = f2bu(fvy * es);
      p[224 + m] = f2bu((fvz*evx - fvx*evz) * INV_SQRT2);
      p[256 + m] = f2bu(w0 * evz);
      p[288 + m] = f2bu(fvz * es);
      p[320 + m] = f2bu((fvx*evy - fvy*evx) * INV_SQRT2);
    } else {
      us* p = P + el * PP;
      #pragma unroll
      for (int q = 0; q < 11; ++q) p[q*32 + m] = 0;
    }
  }
  __syncthreads();

  floatx4 acc[4][2];
  #pragma unroll
  for (int i = 0; i < 4; ++i)
    #pragma unroll
    for (int j = 0; j < 2; ++j) acc[i][j] = (floatx4){0.f,0.f,0.f,0.f};
  int pbase  = (w == 0) ? 0 : 64 + (w - 1) * 96;
  int wkbase = (w == 0) ? 0 : 64;
  int ksteps = (w == 0) ? 2 : 3;
  for (int ks = 0; ks < ksteps; ++ks) {
    short8 af[4], bv[2];
    #pragma unroll
    for (int et = 0; et < 4; ++et)
      af[et] = ld8(&P[(et*16 + nl) * PP + pbase + ks*32 + quad*8]);
    #pragma unroll
    for (int ct = 0; ct < 2; ++ct)
      bv[ct] = ld8(&Wl[(ct*16 + nl) * 160 + wkbase + ks*32 + quad*8]);
    #pragma unroll
    for (int et = 0; et < 4; ++et)
      #pragma unroll
      for (int ct = 0; ct < 2; ++ct)
        acc[et][ct] = mfma16(af[et], bv[ct], acc[et][ct]);
  }
  __syncthreads();

  #pragma unroll
  for (int et = 0; et < 4; ++et)
    #pragma unroll
    for (int ct = 0; ct < 2; ++ct)
      #pragma unroll
      for (int r = 0; r < 4; ++r) {
        int el = et*16 + quad*4 + r;
        R[el * RP + w*32 + ct*16 + nl] = acc[et][ct][r];
      }
  __syncthreads();

  #pragma unroll
  for (int it = 0; it < 8; ++it) {
    int el = (tid >> 5) + it * 8;
    long e = e0 + el;
    if (e >= E) continue;
    int o = m;
    int c = cent[e];
    float4 e1 = *(const float4*)(env1 + (long)c*128 + o*4);
    float sr = R[el * RP + o];
    float vx = R[el * RP + 32 + o];
    float vy = R[el * RP + 64 + o];
    float vz = R[el * RP + 96 + o];
    float q0 = sr * 0.125f * (e1.x * INV_SQRT_N);
    float q1 = (vx*e1.y + vy*e1.z + vz*e1.w) *
               (0.10206207261596577f * INV_SQRT_N * INV_SQRT3);
    scal[e*64 + o]      = f2b(q0);
    scal[e*64 + 32 + o] = f2b(q1);
  }
}

// ---------------------------------------------------------------------------
extern "C" void kernel_launch(void* const* d_in, const int* in_sizes, int n_in,
                              void* d_out, int out_size, void* d_ws, size_t ws_size,
                              hipStream_t stream) {
  const float* coords = (const float*)d_in[0];
  const float* nattr  = (const float*)d_in[1];
  const int*   eidx   = (const int*)d_in[2];
  const float* W2b0   = (const float*)d_in[3];
  const float* W2b1   = (const float*)d_in[4];
  const float* W2b2   = (const float*)d_in[5];
  const float* Wenv0  = (const float*)d_in[6];
  const float* Wlat0  = (const float*)d_in[7];
  const float* Wlat1  = (const float*)d_in[8];
  const float* Ws0    = (const float*)d_in[9];
  const float* Wv0    = (const float*)d_in[10];
  const float* Wenv1  = (const float*)d_in[11];
  const float* Wfin0  = (const float*)d_in[12];
  const float* Wfin1  = (const float*)d_in[13];
  float* out = (float*)d_out;
  int E = in_sizes[2] / 2;     // 320000
  int N = in_sizes[0] / 3;     // 10000

  // workspace carve (~183 MB)
  float* fcut   = (float*)d_ws;                    // E
  float* Yb     = fcut + (size_t)E;                // 4E
  float* env    = Yb + (size_t)E*4;                // 128N
  float* env1   = env + (size_t)N*128;             // 128N
  int*   deg    = (int*)(env1 + (size_t)N*128);    // N
  int*   rowptr = deg + N;                         // N+8
  int*   cursor = rowptr + (N + 8);                // N
  int*   eord   = cursor + N;                      // E
  int*   cent   = eord + E;                        // E
  bf16*  b64    = (bf16*)(cent + E);               // 64E (w_edge)
  bf16*  lat    = b64 + (size_t)E*64;              // 128E
  bf16*  S      = lat + (size_t)E*128;             // 64E (a64/wenv/scal0/wenv1/scal1)
  us* W2b1t  = (us*)(S + (size_t)E*64);            // 128x64
  us* W2b2t  = W2b1t + 128*64;                     // 128x128
  us* Wenv0t = W2b2t + 128*128;                    // 128x128
  us* Wlat0t = Wenv0t + 128*128;                   // 128x192
  us* Wlat1t = Wlat0t + 128*192;                   // 128x128
  us* Wenv1t = Wlat1t + 128*128;                   // 64x128
  us* Wfin0t = Wenv1t + 64*128;                    // 128x192
  us* Wfin1t = Wfin0t + 128*192;                   // 128x128
  us* W2b0p  = Wfin1t + 128*128;                   // 64x64 (zero-padded)
  us* Wmixt  = W2b0p + 64*64;                      // 32x160

  hipMemsetAsync(deg, 0, (size_t)N * sizeof(int), stream);

  dim3 blk(256);
  const float s40  = 0.15811388300841897f;  // 1/sqrt(40)
  const float s64  = 0.125f;
  const float s128 = 0.08838834764831845f;
  const float s192 = 0.07216878364870323f;
  int gB = (E + 63) / 64;
  int gE = (E + 255) / 256;

  // CSR build, slot-ordered geometry, merged weight prep
  k_deg<<<gE, blk, 0, stream>>>(eidx, E, deg);
  k_scan<<<1, 1024, 0, stream>>>(deg, N, rowptr, cursor);
  k_fill<<<gE, blk, 0, stream>>>(eidx, E, cursor, eord, cent);
  k_geom<<<gE, blk, 0, stream>>>(coords, nattr, eidx, eord, E, fcut, Yb, S /*a64*/);
  k_wprep_all<<<dim3(548), blk, 0, stream>>>(
      W2b0, W2b1, W2b2, Wenv0, Wlat0, Wlat1, Wenv1, Wfin0, Wfin1, Ws0, Wv0,
      W2b0p, W2b1t, W2b2t, Wenv0t, Wlat0t, Wlat1t, Wenv1t, Wfin0t, Wfin1t, Wmixt);

  // two-body MLP (3 layers) + Wenv0 tail -> lat, b64(w_edge), wenv
  mfused3s<<<gB, blk, 0, stream>>>(
      S /*a64*/, W2b0p, W2b1t, W2b2t, Wenv0t, lat, b64, S /*wenv*/, fcut,
      s40, s64, s128, E);

  // env gather + scal0 products (fused)
  k_envgp<<<dim3((N*32 + 255) / 256), blk, 0, stream>>>(
      S /*wenv*/, b64, Yb, rowptr, N, env, S /*scal0 (overwrites wenv)*/);

  // latent MLP + residual + Wenv1 tail -> lat, wenv1
  mfuseds<1><<<gB, blk, 0, stream>>>(
      lat, S /*scal0*/, Wlat0t, Wlat1t, Wenv1t, lat, S /*wenv1*/, fcut,
      s192, s128, E);

  // env1 gather
  k_envg<<<dim3((N*32 + 255) / 256), blk, 0, stream>>>(
      S /*wenv1*/, Yb, rowptr, N, env1);

  // MFMA mix -> scal1
  k_mix2<<<gB, blk, 0, stream>>>(
      b64, env, env1, Yb, cent, Wmixt, E, S /*scal1*/);

  // final MLP + residual (no tail)
  mfuseds<0><<<gB, blk, 0, stream>>>(
      lat, S /*scal1*/, Wfin0t, Wfin1t, nullptr, lat, nullptr, fcut,
      s192, s128, E);

  // node segment-sum -> d_out
  k_nodeg<<<dim3((N*128 + 255) / 256), blk, 0, stream>>>(
      lat, rowptr, N, out);
}

// Round 15
// 712.968 us; speedup vs baseline: 1.0821x; 1.0137x over previous
//
#include <hip/hip_runtime.h>
#include <hip/hip_bf16.h>
#include <math.h>

typedef __hip_bfloat16 bf16;
typedef unsigned short us;
typedef __attribute__((ext_vector_type(8))) short short8;
typedef __attribute__((ext_vector_type(4))) float floatx4;

#define INV_SQRT_N 0.17677669529663687f   /* 1/sqrt(32) */
#define INV_SQRT3  0.5773502691896258f
#define INV_SQRT2  0.7071067811865476f
#define C_OLD      0.8944271909999159f    /* 1/sqrt(1.25) */
#define C_NEW      0.4472135954999579f
#define PI_F       3.14159265358979323846f
#define SQRT3_F    1.7320508075688772f
#define BESSEL_PREF 0.6324555320336759f   /* sqrt(2/5) */

__device__ __forceinline__ float b2f(bf16 x) { return __bfloat162float(x); }
__device__ __forceinline__ bf16  f2b(float x) { return __float2bfloat16(x); }
__device__ __forceinline__ us f2bu(float x) {
  bf16 h = f2b(x); us u; __builtin_memcpy(&u, &h, 2); return u;
}
__device__ __forceinline__ float silu_f(float v) { return v / (1.f + __expf(-v)); }
__device__ __forceinline__ floatx4 mfma16(short8 a, short8 b, floatx4 c) {
  return __builtin_amdgcn_mfma_f32_16x16x32_bf16(a, b, c, 0, 0, 0);
}
__device__ __forceinline__ short8 ld8(const void* p) {
  return *reinterpret_cast<const short8*>(p);
}
#define ZERO8 ((short8){0,0,0,0,0,0,0,0})

// ---------------------------------------------------------------------------
// CSR build
// ---------------------------------------------------------------------------
__global__ __launch_bounds__(256) void k_deg(
    const int* __restrict__ eidx, int E, int* __restrict__ deg) {
  int e = blockIdx.x * 256 + threadIdx.x;
  if (e < E) atomicAdd(&deg[eidx[E + e]], 1);
}

__global__ __launch_bounds__(1024) void k_scan(
    const int* __restrict__ deg, int N,
    int* __restrict__ rowptr, int* __restrict__ cursor) {
  __shared__ int part[1024];
  int t = threadIdx.x;
  int C = (N + 1023) / 1024;
  int base = t * C;
  int s = 0;
  for (int i = 0; i < C; ++i) { int idx = base + i; if (idx < N) s += deg[idx]; }
  part[t] = s;
  __syncthreads();
  for (int off = 1; off < 1024; off <<= 1) {
    int v = (t >= off) ? part[t - off] : 0;
    __syncthreads();
    part[t] += v;
    __syncthreads();
  }
  int excl = (t == 0) ? 0 : part[t - 1];
  for (int i = 0; i < C; ++i) {
    int idx = base + i;
    if (idx < N) { rowptr[idx] = excl; cursor[idx] = excl; excl += deg[idx]; }
  }
  if (t == 0) rowptr[N] = part[1023];
}

__global__ __launch_bounds__(256) void k_fill(
    const int* __restrict__ eidx, int E, int* __restrict__ cursor,
    int* __restrict__ eord, int* __restrict__ cent) {
  int e = blockIdx.x * 256 + threadIdx.x;
  if (e >= E) return;
  int c = eidx[E + e];
  int slot = atomicAdd(&cursor[c], 1);
  eord[slot] = e;
  cent[slot] = c;
}

// ---------------------------------------------------------------------------
// merged weight prep: fp32 W[k][n] -> bf16 Wt[n][k]; W2b0 padded to 64x64.
// ---------------------------------------------------------------------------
__device__ __forceinline__ void wp(const float* W, us* Wt, int K, int NOUT, int t) {
  int n = t / K, k = t % K;
  Wt[n * K + k] = f2bu(W[k * NOUT + n]);
}

__global__ __launch_bounds__(256) void k_wprep_all(
    const float* W2b0, const float* W2b1, const float* W2b2,
    const float* Wenv0, const float* Wlat0, const float* Wlat1,
    const float* Wenv1, const float* Wfin0, const float* Wfin1,
    const float* Ws0, const float* Wv0,
    us* W2b0p, us* W2b1t, us* W2b2t, us* Wenv0t, us* Wlat0t, us* Wlat1t,
    us* Wenv1t, us* Wfin0t, us* Wfin1t, us* Wmixt) {
  int t = blockIdx.x * 256 + threadIdx.x;
  if (t < 8192)  { wp(W2b1,  W2b1t,  64, 128, t); return; } t -= 8192;
  if (t < 16384) { wp(W2b2,  W2b2t, 128, 128, t); return; } t -= 16384;
  if (t < 16384) { wp(Wenv0, Wenv0t,128, 128, t); return; } t -= 16384;
  if (t < 24576) { wp(Wlat0, Wlat0t,192, 128, t); return; } t -= 24576;
  if (t < 16384) { wp(Wlat1, Wlat1t,128, 128, t); return; } t -= 16384;
  if (t < 8192)  { wp(Wenv1, Wenv1t,128,  64, t); return; } t -= 8192;
  if (t < 24576) { wp(Wfin0, Wfin0t,192, 128, t); return; } t -= 24576;
  if (t < 16384) { wp(Wfin1, Wfin1t,128, 128, t); return; } t -= 16384;
  if (t < 4096)  {
    int n = t >> 6, k = t & 63;
    W2b0p[n * 64 + k] = (k < 40) ? f2bu(W2b0[k * 64 + n]) : 0;
    return;
  } t -= 4096;
  if (t < 5120) {
    int o = t / 160, k = t % 160;
    float v = (k < 64) ? Ws0[k * 32 + o] : Wv0[(k - 64) * 32 + o];
    Wmixt[o * 160 + k] = f2bu(v);
  }
}

// ---------------------------------------------------------------------------
// env gather (CSR, slot-ordered)
// ---------------------------------------------------------------------------
__global__ __launch_bounds__(256) void k_envg(
    const bf16* __restrict__ wenv, const float* __restrict__ Yb,
    const int* __restrict__ rowptr, int N, float* __restrict__ env) {
  int t = blockIdx.x * 256 + threadIdx.x;
  if (t >= N * 32) return;
  int n = t >> 5, m = t & 31;
  int j0 = rowptr[n], j1 = rowptr[n + 1];
  float a0 = 0.f, a1 = 0.f, a2 = 0.f, a3 = 0.f;
  for (int j = j0; j < j1; ++j) {
    float w0 = b2f(wenv[(long)j*64 + 2*m]);
    float w1 = b2f(wenv[(long)j*64 + 2*m + 1]);
    float4 y = *reinterpret_cast<const float4*>(&Yb[(long)j*4]);
    a0 += w0;
    a1 += w1 * y.y;
    a2 += w1 * y.z;
    a3 += w1 * y.w;
  }
  *reinterpret_cast<float4*>(&env[(long)n*128 + m*4]) = make_float4(a0, a1, a2, a3);
}

// ---------------------------------------------------------------------------
// node gather (CSR, slot-ordered) -> d_out
// ---------------------------------------------------------------------------
__global__ __launch_bounds__(256) void k_nodeg(
    const bf16* __restrict__ lat, const int* __restrict__ rowptr,
    int N, float* __restrict__ out) {
  int t = blockIdx.x * 256 + threadIdx.x;
  if (t >= N * 128) return;
  int n = t >> 7, j = t & 127;
  int j0 = rowptr[n], j1 = rowptr[n + 1];
  float s = 0.f;
  for (int q = j0; q < j1; ++q)
    s += b2f(lat[(long)q*128 + j]);
  out[t] = s * INV_SQRT_N;
}

// ---------------------------------------------------------------------------
// mfused3s: geometry+a64 built IN LDS (no global a64) -> 3-layer MLP -> lat,
// then tail GEMM lat@Wenv0 -> split b64(w_edge) / wenv. Writes fcut/Yb.
// ---------------------------------------------------------------------------
__global__ __launch_bounds__(256) void mfused3s(
    const float* __restrict__ coords, const float* __restrict__ nattr,
    const int* __restrict__ eidx, const int* __restrict__ eord,
    const us* __restrict__ W0p, const us* __restrict__ W1t,
    const us* __restrict__ W2t, const us* __restrict__ Wenv0t,
    bf16* __restrict__ lat, bf16* __restrict__ b64, bf16* __restrict__ wenv,
    float* __restrict__ fcut, float* __restrict__ Yb,
    float s40, float s64s, float s128, int E) {
  constexpr int AP = 72, HP = 136;
  __shared__ __align__(16) us SB[64 * 144];   // As | H0 ; Hs aliases whole
  us* As = SB;
  us* H0 = SB + 64 * AP;
  us* Hs = SB;
  int tid = threadIdx.x;
  int lane = tid & 63, w = tid >> 6;
  int nl = lane & 15, quad = lane >> 4;
  long e0 = (long)blockIdx.x * 64;

  short8 w0f[2], w1f[2][2], w2f[4][2];
  #pragma unroll
  for (int kc = 0; kc < 2; ++kc)
    w0f[kc] = ld8(W0p + (w*16 + nl) * 64 + kc*32 + quad*8);
  #pragma unroll
  for (int kc = 0; kc < 2; ++kc)
    #pragma unroll
    for (int ct = 0; ct < 2; ++ct)
      w1f[kc][ct] = ld8(W1t + (long)(w*32 + ct*16 + nl) * 64 + kc*32 + quad*8);
  #pragma unroll
  for (int kc = 0; kc < 4; ++kc)
    #pragma unroll
    for (int ct = 0; ct < 2; ++ct)
      w2f[kc][ct] = ld8(W2t + (long)(w*32 + ct*16 + nl) * 128 + kc*32 + quad*8);

  // geometry + a64 build directly into As. quarter q: 0=nattr[c],1=nattr[s],
  // 2=geometry+ef (+fcut/Yb global), 3=zero pad cols 40-63.
  {
    int row = tid & 63, q = tid >> 6;
    long eg = e0 + row;
    if (q == 3) {
      for (int i = 40; i < 64; ++i) As[row * AP + i] = 0;
    } else if (eg < E) {
      int e = eord[eg];
      int sN = eidx[e], cN = eidx[E + e];
      if (q == 0) {
        #pragma unroll
        for (int i = 0; i < 16; ++i)
          As[row * AP + i] = f2bu(nattr[(long)cN*16 + i]);
      } else if (q == 1) {
        #pragma unroll
        for (int i = 0; i < 16; ++i)
          As[row * AP + 16 + i] = f2bu(nattr[(long)sN*16 + i]);
      } else { // q == 2
        float dx = coords[cN*3+0] - coords[sN*3+0];
        float dy = coords[cN*3+1] - coords[sN*3+1];
        float dz = coords[cN*3+2] - coords[sN*3+2];
        float r = sqrtf(dx*dx + dy*dy + dz*dz + 1e-12f);
        float u = r * 0.2f;
        float u3 = u*u*u;
        float u6 = u3*u3, u7 = u6*u, u8 = u7*u;
        float fc = 1.f - 28.f*u6 + 48.f*u7 - 21.f*u8;
        fc = (u < 1.f) ? fc : 0.f;
        float inv_r = 1.f / r;
        fcut[eg] = fc;
        Yb[eg*4+0] = 1.f;
        Yb[eg*4+1] = SQRT3_F * dx * inv_r;
        Yb[eg*4+2] = SQRT3_F * dy * inv_r;
        Yb[eg*4+3] = SQRT3_F * dz * inv_r;
        float pref = BESSEL_PREF * inv_r * fc;
        #pragma unroll
        for (int n = 1; n <= 8; ++n)
          As[row * AP + 32 + n - 1] = f2bu(pref * sinf((float)n * PI_F * u));
      }
    } else {
      if (q == 0) {
        for (int i = 0; i < 16; ++i) As[row * AP + i] = 0;
      } else if (q == 1) {
        for (int i = 0; i < 16; ++i) As[row * AP + 16 + i] = 0;
      } else {
        for (int i = 32; i < 40; ++i) As[row * AP + i] = 0;
      }
    }
  }
  __syncthreads();

  // layer 0: 64(40p) -> 64, silu -> H0
  floatx4 a0[4];
  #pragma unroll
  for (int i = 0; i < 4; ++i) a0[i] = (floatx4){0.f,0.f,0.f,0.f};
  #pragma unroll
  for (int kc = 0; kc < 2; ++kc) {
    short8 af[4];
    #pragma unroll
    for (int et = 0; et < 4; ++et)
      af[et] = ld8(&As[(et*16 + nl) * AP + kc*32 + quad*8]);
    #pragma unroll
    for (int et = 0; et < 4; ++et) a0[et] = mfma16(af[et], w0f[kc], a0[et]);
  }
  #pragma unroll
  for (int et = 0; et < 4; ++et)
    #pragma unroll
    for (int r = 0; r < 4; ++r)
      H0[(et*16 + quad*4 + r) * AP + w*16 + nl] = f2bu(silu_f(a0[et][r] * s40));
  __syncthreads();

  // layer 1: 64 -> 128, silu (regs)
  floatx4 acc[4][2];
  #pragma unroll
  for (int i = 0; i < 4; ++i)
    #pragma unroll
    for (int j = 0; j < 2; ++j) acc[i][j] = (floatx4){0.f,0.f,0.f,0.f};
  #pragma unroll
  for (int kc = 0; kc < 2; ++kc) {
    short8 af[4];
    #pragma unroll
    for (int et = 0; et < 4; ++et)
      af[et] = ld8(&H0[(et*16 + nl) * AP + kc*32 + quad*8]);
    #pragma unroll
    for (int et = 0; et < 4; ++et)
      #pragma unroll
      for (int ct = 0; ct < 2; ++ct)
        acc[et][ct] = mfma16(af[et], w1f[kc][ct], acc[et][ct]);
  }
  __syncthreads();   // H0 reads done before Hs overwrite

  #pragma unroll
  for (int et = 0; et < 4; ++et)
    #pragma unroll
    for (int ct = 0; ct < 2; ++ct)
      #pragma unroll
      for (int r = 0; r < 4; ++r)
        Hs[(et*16 + quad*4 + r) * HP + w*32 + ct*16 + nl] =
            f2bu(silu_f(acc[et][ct][r] * s64s));
  __syncthreads();

  // layer 2: 128 -> 128, *fcut -> lat, keep bf16 in Hs for tail
  #pragma unroll
  for (int i = 0; i < 4; ++i)
    #pragma unroll
    for (int j = 0; j < 2; ++j) acc[i][j] = (floatx4){0.f,0.f,0.f,0.f};
  #pragma unroll
  for (int kc = 0; kc < 4; ++kc) {
    short8 af[4];
    #pragma unroll
    for (int et = 0; et < 4; ++et)
      af[et] = ld8(&Hs[(et*16 + nl) * HP + kc*32 + quad*8]);
    #pragma unroll
    for (int et = 0; et < 4; ++et)
      #pragma unroll
      for (int ct = 0; ct < 2; ++ct)
        acc[et][ct] = mfma16(af[et], w2f[kc][ct], acc[et][ct]);
  }

  short8 wef[4][2];
  #pragma unroll
  for (int kc = 0; kc < 4; ++kc)
    #pragma unroll
    for (int ct = 0; ct < 2; ++ct)
      wef[kc][ct] = ld8(Wenv0t + (long)(w*32 + ct*16 + nl) * 128 + kc*32 + quad*8);

  __syncthreads();   // layer-2 Hs reads done before overwrite

  #pragma unroll
  for (int et = 0; et < 4; ++et)
    #pragma unroll
    for (int ct = 0; ct < 2; ++ct)
      #pragma unroll
      for (int r = 0; r < 4; ++r) {
        long eg = e0 + et*16 + quad*4 + r;
        int col = w*32 + ct*16 + nl;
        us lv = 0;
        if (eg < E) {
          lv = f2bu(acc[et][ct][r] * s128 * fcut[eg]);
          bf16 h; __builtin_memcpy(&h, &lv, 2);
          lat[eg * 128 + col] = h;
        }
        Hs[(et*16 + quad*4 + r) * HP + col] = lv;
      }
  __syncthreads();

  // tail GEMM: latf(128) @ Wenv0 -> 128, split b64 / wenv
  #pragma unroll
  for (int i = 0; i < 4; ++i)
    #pragma unroll
    for (int j = 0; j < 2; ++j) acc[i][j] = (floatx4){0.f,0.f,0.f,0.f};
  #pragma unroll
  for (int kc = 0; kc < 4; ++kc) {
    short8 af[4];
    #pragma unroll
    for (int et = 0; et < 4; ++et)
      af[et] = ld8(&Hs[(et*16 + nl) * HP + kc*32 + quad*8]);
    #pragma unroll
    for (int et = 0; et < 4; ++et)
      #pragma unroll
      for (int ct = 0; ct < 2; ++ct)
        acc[et][ct] = mfma16(af[et], wef[kc][ct], acc[et][ct]);
  }
  #pragma unroll
  for (int et = 0; et < 4; ++et)
    #pragma unroll
    for (int ct = 0; ct < 2; ++ct)
      #pragma unroll
      for (int r = 0; r < 4; ++r) {
        long eg = e0 + et*16 + quad*4 + r;
        if (eg >= E) continue;
        int col = w*32 + ct*16 + nl;
        float v = acc[et][ct][r] * s128;
        if (col < 64) b64[eg * 64 + col] = f2b(v);
        else          wenv[eg * 64 + (col - 64)] = f2b(v);
      }
}

// ---------------------------------------------------------------------------
// mf_lat: scal0 computed in prologue (wedge,env,Yb,cent) -> As cols 128-191,
// [lat|scal0] ->silu 128 ->128, residual into lat, tail newlat@Wenv1 -> wenv1.
// ---------------------------------------------------------------------------
__global__ __launch_bounds__(256) void mf_lat(
    const bf16* __restrict__ A, const bf16* __restrict__ wedge,
    const float* __restrict__ env, const float* __restrict__ Yb,
    const int* __restrict__ cent,
    const us* __restrict__ W0t, const us* __restrict__ W1t,
    const us* __restrict__ Wenv1t,
    bf16* __restrict__ outb, bf16* __restrict__ wenv1,
    const float* __restrict__ fcut,
    float scale0, float scale1, int E) {
  constexpr int K = 192, KP = 200, NC0 = 6, HP = 136;
  __shared__ __align__(16) us SB[64 * KP];
  us* As = SB;
  us* Hs = SB;
  int tid = threadIdx.x;
  int lane = tid & 63, w = tid >> 6;
  int nl = lane & 15, quad = lane >> 4;
  long e0 = (long)blockIdx.x * 64;
  int m = tid & 31;

  // prologue: scal0 = [p0|p1] directly into As cols 128-191
  #pragma unroll
  for (int it = 0; it < 8; ++it) {
    int el = (tid >> 5) + it * 8;
    long e = e0 + el;
    us v0 = 0, v1 = 0;
    if (e < E) {
      int c = cent[e];
      float w0 = b2f(wedge[e*64 + 2*m]), w1 = b2f(wedge[e*64 + 2*m + 1]);
      float4 ev = *(const float4*)(env + (long)c*128 + m*4);
      float4 y  = *(const float4*)(Yb + e*4);
      float es  = ev.x * INV_SQRT_N;
      float evx = ev.y * INV_SQRT_N, evy = ev.z * INV_SQRT_N, evz = ev.w * INV_SQRT_N;
      float fvx = w1*y.y, fvy = w1*y.z, fvz = w1*y.w;
      v0 = f2bu(w0 * es);
      v1 = f2bu((fvx*evx + fvy*evy + fvz*evz) * INV_SQRT3);
    }
    As[el * KP + 128 + m] = v0;
    As[el * KP + 160 + m] = v1;
  }

  // stage lat cols 0-127
  #pragma unroll
  for (int it = 0; it < 4; ++it) {
    int i = tid + it * 256;
    int row = i >> 4, col = (i & 15) * 8;
    long eg = e0 + row;
    short8 v = (eg < E) ? ld8(A + eg * 128 + col) : ZERO8;
    *(short8*)&As[row * KP + col] = v;
  }

  short8 w0f[NC0][2];
  #pragma unroll
  for (int kc = 0; kc < NC0; ++kc)
    #pragma unroll
    for (int ct = 0; ct < 2; ++ct)
      w0f[kc][ct] = ld8(W0t + (long)(w*32 + ct*16 + nl) * K + kc*32 + quad*8);
  __syncthreads();

  // layer 1
  floatx4 acc[4][2];
  #pragma unroll
  for (int i = 0; i < 4; ++i)
    #pragma unroll
    for (int j = 0; j < 2; ++j) acc[i][j] = (floatx4){0.f,0.f,0.f,0.f};
  #pragma unroll
  for (int kc = 0; kc < NC0; ++kc) {
    short8 af[4];
    #pragma unroll
    for (int et = 0; et < 4; ++et)
      af[et] = ld8(&As[(et*16 + nl) * KP + kc*32 + quad*8]);
    #pragma unroll
    for (int et = 0; et < 4; ++et)
      #pragma unroll
      for (int ct = 0; ct < 2; ++ct)
        acc[et][ct] = mfma16(af[et], w0f[kc][ct], acc[et][ct]);
  }

  short8 w1f[4][2];
  #pragma unroll
  for (int kc = 0; kc < 4; ++kc)
    #pragma unroll
    for (int ct = 0; ct < 2; ++ct)
      w1f[kc][ct] = ld8(W1t + (long)(w*32 + ct*16 + nl) * 128 + kc*32 + quad*8);

  __syncthreads();   // As reads done before Hs overwrite

  #pragma unroll
  for (int et = 0; et < 4; ++et)
    #pragma unroll
    for (int ct = 0; ct < 2; ++ct)
      #pragma unroll
      for (int r = 0; r < 4; ++r)
        Hs[(et*16 + quad*4 + r) * HP + w*32 + ct*16 + nl] =
            f2bu(silu_f(acc[et][ct][r] * scale0));
  __syncthreads();

  // layer 2
  #pragma unroll
  for (int i = 0; i < 4; ++i)
    #pragma unroll
    for (int j = 0; j < 2; ++j) acc[i][j] = (floatx4){0.f,0.f,0.f,0.f};
  #pragma unroll
  for (int kc = 0; kc < 4; ++kc) {
    short8 af[4];
    #pragma unroll
    for (int et = 0; et < 4; ++et)
      af[et] = ld8(&Hs[(et*16 + nl) * HP + kc*32 + quad*8]);
    #pragma unroll
    for (int et = 0; et < 4; ++et)
      #pragma unroll
      for (int ct = 0; ct < 2; ++ct)
        acc[et][ct] = mfma16(af[et], w1f[kc][ct], acc[et][ct]);
  }

  // residual + stash newlat into Hs for tail
  short8 wef[4];
  #pragma unroll
  for (int kc = 0; kc < 4; ++kc)
    wef[kc] = ld8(Wenv1t + (long)(w*16 + nl) * 128 + kc*32 + quad*8);

  __syncthreads();   // layer-2 Hs reads done before overwrite

  #pragma unroll
  for (int et = 0; et < 4; ++et)
    #pragma unroll
    for (int ct = 0; ct < 2; ++ct)
      #pragma unroll
      for (int r = 0; r < 4; ++r) {
        long eg = e0 + et*16 + quad*4 + r;
        int col = w*32 + ct*16 + nl;
        us lv = 0;
        if (eg < E) {
          float v = acc[et][ct][r] * scale1 * fcut[eg];
          long idx = eg * 128 + col;
          lv = f2bu(C_OLD * b2f(outb[idx]) + C_NEW * v);
          bf16 h; __builtin_memcpy(&h, &lv, 2);
          outb[idx] = h;
        }
        Hs[(et*16 + quad*4 + r) * HP + col] = lv;
      }
  __syncthreads();

  // tail: newlat(128) @ Wenv1 -> 64 cols
  floatx4 acc2[4];
  #pragma unroll
  for (int i = 0; i < 4; ++i) acc2[i] = (floatx4){0.f,0.f,0.f,0.f};
  #pragma unroll
  for (int kc = 0; kc < 4; ++kc) {
    short8 af[4];
    #pragma unroll
    for (int et = 0; et < 4; ++et)
      af[et] = ld8(&Hs[(et*16 + nl) * HP + kc*32 + quad*8]);
    #pragma unroll
    for (int et = 0; et < 4; ++et)
      acc2[et] = mfma16(af[et], wef[kc], acc2[et]);
  }
  #pragma unroll
  for (int et = 0; et < 4; ++et)
    #pragma unroll
    for (int r = 0; r < 4; ++r) {
      long eg = e0 + et*16 + quad*4 + r;
      if (eg >= E) continue;
      wenv1[eg * 64 + w*16 + nl] = f2b(acc2[et][r] * 0.08838834764831845f);
    }
}

// ---------------------------------------------------------------------------
// mf_fin: mix prologue (products->P, wave-job MFMA, R, q0/q1 in regs) ->
// scal1 into As cols 128-191, then [lat|scal1] MLP + residual into lat.
// ---------------------------------------------------------------------------
__global__ __launch_bounds__(256) void mf_fin(
    const bf16* __restrict__ A, const bf16* __restrict__ wedge,
    const float* __restrict__ env, const float* __restrict__ env1,
    const float* __restrict__ Yb, const int* __restrict__ cent,
    const us* __restrict__ Wm,
    const us* __restrict__ W0t, const us* __restrict__ W1t,
    bf16* __restrict__ outb, const float* __restrict__ fcut,
    float scale0, float scale1, int E) {
  constexpr int K = 192, KP = 200, HP = 136, PP = 360, RP = 132, NC0 = 6;
  __shared__ __align__(16) us SB[64 * PP];   // P / R / As / Hs all alias
  __shared__ __align__(16) us Wl[32 * 160];
  us* P = SB;
  float* R = (float*)SB;
  us* As = SB;
  us* Hs = SB;
  int tid = threadIdx.x;
  int lane = tid & 63, w = tid >> 6;
  int nl = lane & 15, quad = lane >> 4;
  long e0 = (long)blockIdx.x * 64;
  int m = tid & 31;

  for (int i = tid; i < 640; i += 256)
    *(short8*)&Wl[i * 8] = ld8(Wm + i * 8);

  // phase 1: products -> P
  #pragma unroll
  for (int it = 0; it < 8; ++it) {
    int el = (tid >> 5) + it * 8;
    long e = e0 + el;
    if (e < E) {
      int c = cent[e];
      float w0 = b2f(wedge[e*64 + 2*m]), w1 = b2f(wedge[e*64 + 2*m + 1]);
      float4 ev4 = *(const float4*)(env + (long)c*128 + m*4);
      float4 y   = *(const float4*)(Yb + e*4);
      float es  = ev4.x * INV_SQRT_N;
      float evx = ev4.y * INV_SQRT_N, evy = ev4.z * INV_SQRT_N, evz = ev4.w * INV_SQRT_N;
      float fvx = w1*y.y, fvy = w1*y.z, fvz = w1*y.w;
      us* p = P + el * PP;
      p[m]       = f2bu(w0 * es);
      p[32 + m]  = f2bu((fvx*evx + fvy*evy + fvz*evz) * INV_SQRT3);
      p[64 + m]  = f2bu(w0 * evx);
      p[96 + m]  = f2bu(fvx * es);
      p[128 + m] = f2bu((fvy*evz - fvz*evy) * INV_SQRT2);
      p[160 + m] = f2bu(w0 * evy);
      p[192 + m] = f2bu(fvy * es);
      p[224 + m] = f2bu((fvz*evx - fvx*evz) * INV_SQRT2);
      p[256 + m] = f2bu(w0 * evz);
      p[288 + m] = f2bu(fvz * es);
      p[320 + m] = f2bu((fvx*evy - fvy*evx) * INV_SQRT2);
    } else {
      us* p = P + el * PP;
      #pragma unroll
      for (int q = 0; q < 11; ++q) p[q*32 + m] = 0;
    }
  }
  __syncthreads();

  // phase 2: wave-job mix MFMAs
  floatx4 acc[4][2];
  #pragma unroll
  for (int i = 0; i < 4; ++i)
    #pragma unroll
    for (int j = 0; j < 2; ++j) acc[i][j] = (floatx4){0.f,0.f,0.f,0.f};
  {
    int pbase  = (w == 0) ? 0 : 64 + (w - 1) * 96;
    int wkbase = (w == 0) ? 0 : 64;
    int ksteps = (w == 0) ? 2 : 3;
    for (int ks = 0; ks < ksteps; ++ks) {
      short8 af[4], bv[2];
      #pragma unroll
      for (int et = 0; et < 4; ++et)
        af[et] = ld8(&P[(et*16 + nl) * PP + pbase + ks*32 + quad*8]);
      #pragma unroll
      for (int ct = 0; ct < 2; ++ct)
        bv[ct] = ld8(&Wl[(ct*16 + nl) * 160 + wkbase + ks*32 + quad*8]);
      #pragma unroll
      for (int et = 0; et < 4; ++et)
        #pragma unroll
        for (int ct = 0; ct < 2; ++ct)
          acc[et][ct] = mfma16(af[et], bv[ct], acc[et][ct]);
    }
  }
  __syncthreads();   // P reads done before R overwrite

  #pragma unroll
  for (int et = 0; et < 4; ++et)
    #pragma unroll
    for (int ct = 0; ct < 2; ++ct)
      #pragma unroll
      for (int r = 0; r < 4; ++r) {
        int el = et*16 + quad*4 + r;
        R[el * RP + w*32 + ct*16 + nl] = acc[et][ct][r];
      }
  __syncthreads();

  // phase 3: q0/q1 per (el,m) into regs
  float qa[8], qb[8];
  #pragma unroll
  for (int it = 0; it < 8; ++it) {
    int el = (tid >> 5) + it * 8;
    long e = e0 + el;
    qa[it] = 0.f; qb[it] = 0.f;
    if (e < E) {
      int c = cent[e];
      float4 e1 = *(const float4*)(env1 + (long)c*128 + m*4);
      float sr = R[el * RP + m];
      float vx = R[el * RP + 32 + m];
      float vy = R[el * RP + 64 + m];
      float vz = R[el * RP + 96 + m];
      qa[it] = sr * 0.125f * (e1.x * INV_SQRT_N);
      qb[it] = (vx*e1.y + vy*e1.z + vz*e1.w) *
               (0.10206207261596577f * INV_SQRT_N * INV_SQRT3);
    }
  }
  __syncthreads();   // R reads done before As overwrite

  // phase 4: stage [lat | scal1] into As
  #pragma unroll
  for (int it = 0; it < 4; ++it) {
    int i = tid + it * 256;
    int row = i >> 4, col = (i & 15) * 8;
    long eg = e0 + row;
    short8 v = (eg < E) ? ld8(A + eg * 128 + col) : ZERO8;
    *(short8*)&As[row * KP + col] = v;
  }
  #pragma unroll
  for (int it = 0; it < 8; ++it) {
    int el = (tid >> 5) + it * 8;
    As[el * KP + 128 + m] = f2bu(qa[it]);
    As[el * KP + 160 + m] = f2bu(qb[it]);
  }

  short8 w0f[NC0][2];
  #pragma unroll
  for (int kc = 0; kc < NC0; ++kc)
    #pragma unroll
    for (int ct = 0; ct < 2; ++ct)
      w0f[kc][ct] = ld8(W0t + (long)(w*32 + ct*16 + nl) * K + kc*32 + quad*8);
  __syncthreads();

  // layer 1
  #pragma unroll
  for (int i = 0; i < 4; ++i)
    #pragma unroll
    for (int j = 0; j < 2; ++j) acc[i][j] = (floatx4){0.f,0.f,0.f,0.f};
  #pragma unroll
  for (int kc = 0; kc < NC0; ++kc) {
    short8 af[4];
    #pragma unroll
    for (int et = 0; et < 4; ++et)
      af[et] = ld8(&As[(et*16 + nl) * KP + kc*32 + quad*8]);
    #pragma unroll
    for (int et = 0; et < 4; ++et)
      #pragma unroll
      for (int ct = 0; ct < 2; ++ct)
        acc[et][ct] = mfma16(af[et], w0f[kc][ct], acc[et][ct]);
  }

  short8 w1f[4][2];
  #pragma unroll
  for (int kc = 0; kc < 4; ++kc)
    #pragma unroll
    for (int ct = 0; ct < 2; ++ct)
      w1f[kc][ct] = ld8(W1t + (long)(w*32 + ct*16 + nl) * 128 + kc*32 + quad*8);

  __syncthreads();

  #pragma unroll
  for (int et = 0; et < 4; ++et)
    #pragma unroll
    for (int ct = 0; ct < 2; ++ct)
      #pragma unroll
      for (int r = 0; r < 4; ++r)
        Hs[(et*16 + quad*4 + r) * HP + w*32 + ct*16 + nl] =
            f2bu(silu_f(acc[et][ct][r] * scale0));
  __syncthreads();

  // layer 2
  #pragma unroll
  for (int i = 0; i < 4; ++i)
    #pragma unroll
    for (int j = 0; j < 2; ++j) acc[i][j] = (floatx4){0.f,0.f,0.f,0.f};
  #pragma unroll
  for (int kc = 0; kc < 4; ++kc) {
    short8 af[4];
    #pragma unroll
    for (int et = 0; et < 4; ++et)
      af[et] = ld8(&Hs[(et*16 + nl) * HP + kc*32 + quad*8]);
    #pragma unroll
    for (int et = 0; et < 4; ++et)
      #pragma unroll
      for (int ct = 0; ct < 2; ++ct)
        acc[et][ct] = mfma16(af[et], w1f[kc][ct], acc[et][ct]);
  }

  // residual epilogue
  #pragma unroll
  for (int et = 0; et < 4; ++et)
    #pragma unroll
    for (int ct = 0; ct < 2; ++ct)
      #pragma unroll
      for (int r = 0; r < 4; ++r) {
        long eg = e0 + et*16 + quad*4 + r;
        if (eg >= E) continue;
        int col = w*32 + ct*16 + nl;
        float v = acc[et][ct][r] * scale1 * fcut[eg];
        long idx = eg * 128 + col;
        outb[idx] = f2b(C_OLD * b2f(outb[idx]) + C_NEW * v);
      }
}

// ---------------------------------------------------------------------------
extern "C" void kernel_launch(void* const* d_in, const int* in_sizes, int n_in,
                              void* d_out, int out_size, void* d_ws, size_t ws_size,
                              hipStream_t stream) {
  const float* coords = (const float*)d_in[0];
  const float* nattr  = (const float*)d_in[1];
  const int*   eidx   = (const int*)d_in[2];
  const float* W2b0   = (const float*)d_in[3];
  const float* W2b1   = (const float*)d_in[4];
  const float* W2b2   = (const float*)d_in[5];
  const float* Wenv0  = (const float*)d_in[6];
  const float* Wlat0  = (const float*)d_in[7];
  const float* Wlat1  = (const float*)d_in[8];
  const float* Ws0    = (const float*)d_in[9];
  const float* Wv0    = (const float*)d_in[10];
  const float* Wenv1  = (const float*)d_in[11];
  const float* Wfin0  = (const float*)d_in[12];
  const float* Wfin1  = (const float*)d_in[13];
  float* out = (float*)d_out;
  int E = in_sizes[2] / 2;     // 320000
  int N = in_sizes[0] / 3;     // 10000

  // workspace carve
  float* fcut   = (float*)d_ws;                    // E
  float* Yb     = fcut + (size_t)E;                // 4E
  float* env    = Yb + (size_t)E*4;                // 128N
  float* env1   = env + (size_t)N*128;             // 128N
  int*   deg    = (int*)(env1 + (size_t)N*128);    // N
  int*   rowptr = deg + N;                         // N+8
  int*   cursor = rowptr + (N + 8);                // N
  int*   eord   = cursor + N;                      // E
  int*   cent   = eord + E;                        // E
  bf16*  b64    = (bf16*)(cent + E);               // 64E (w_edge)
  bf16*  lat    = b64 + (size_t)E*64;              // 128E
  bf16*  S      = lat + (size_t)E*128;             // 64E (wenv then wenv1)
  us* W2b1t  = (us*)(S + (size_t)E*64);            // 128x64
  us* W2b2t  = W2b1t + 128*64;                     // 128x128
  us* Wenv0t = W2b2t + 128*128;                    // 128x128
  us* Wlat0t = Wenv0t + 128*128;                   // 128x192
  us* Wlat1t = Wlat0t + 128*192;                   // 128x128
  us* Wenv1t = Wlat1t + 128*128;                   // 64x128
  us* Wfin0t = Wenv1t + 64*128;                    // 128x192
  us* Wfin1t = Wfin0t + 128*192;                   // 128x128
  us* W2b0p  = Wfin1t + 128*128;                   // 64x64 (zero-padded)
  us* Wmixt  = W2b0p + 64*64;                      // 32x160

  hipMemsetAsync(deg, 0, (size_t)N * sizeof(int), stream);

  dim3 blk(256);
  const float s40  = 0.15811388300841897f;  // 1/sqrt(40)
  const float s64  = 0.125f;
  const float s128 = 0.08838834764831845f;
  const float s192 = 0.07216878364870323f;
  int gB = (E + 63) / 64;
  int gE = (E + 255) / 256;

  // CSR build + weight prep
  k_deg<<<gE, blk, 0, stream>>>(eidx, E, deg);
  k_scan<<<1, 1024, 0, stream>>>(deg, N, rowptr, cursor);
  k_fill<<<gE, blk, 0, stream>>>(eidx, E, cursor, eord, cent);
  k_wprep_all<<<dim3(548), blk, 0, stream>>>(
      W2b0, W2b1, W2b2, Wenv0, Wlat0, Wlat1, Wenv1, Wfin0, Wfin1, Ws0, Wv0,
      W2b0p, W2b1t, W2b2t, Wenv0t, Wlat0t, Wlat1t, Wenv1t, Wfin0t, Wfin1t, Wmixt);

  // geometry + two-body MLP + Wenv0 tail -> fcut, Yb, lat, b64, wenv
  mfused3s<<<gB, blk, 0, stream>>>(
      coords, nattr, eidx, eord, W2b0p, W2b1t, W2b2t, Wenv0t,
      lat, b64, S /*wenv*/, fcut, Yb, s40, s64, s128, E);

  // env gather
  k_envg<<<dim3((N*32 + 255) / 256), blk, 0, stream>>>(
      S /*wenv*/, Yb, rowptr, N, env);

  // latent MLP (scal0 prologue) + residual + Wenv1 tail -> lat, wenv1
  mf_lat<<<gB, blk, 0, stream>>>(
      lat, b64, env, Yb, cent, Wlat0t, Wlat1t, Wenv1t,
      lat, S /*wenv1*/, fcut, s192, s128, E);

  // env1 gather
  k_envg<<<dim3((N*32 + 255) / 256), blk, 0, stream>>>(
      S /*wenv1*/, Yb, rowptr, N, env1);

  // final MLP (mix prologue) + residual -> lat
  mf_fin<<<gB, blk, 0, stream>>>(
      lat, b64, env, env1, Yb, cent, Wmixt, Wfin0t, Wfin1t,
      lat, fcut, s192, s128, E);

  // node segment-sum -> d_out
  k_nodeg<<<dim3((N*128 + 255) / 256), blk, 0, stream>>>(
      lat, rowptr, N, out);
}